// Round 2
// baseline (277.343 us; speedup 1.0000x reference)
//
#include <hip/hip_runtime.h>

typedef __bf16 bf16_t;
typedef bf16_t bf16x8 __attribute__((ext_vector_type(8)));
typedef float f32x4 __attribute__((ext_vector_type(4)));
typedef unsigned short u16;
typedef unsigned int u32;

__device__ __forceinline__ u16 f2bf(float f) {
  union { float f; u32 u; } v; v.f = f;
  u32 r = v.u + 0x7fffu + ((v.u >> 16) & 1u);
  return (u16)(r >> 16);
}

// ---------------- GroupNorm: x[B,C,N] fp32 -> xn_t[B,N,C] bf16 -----------------
__global__ __launch_bounds__(1024) void gn_kernel(const float* __restrict__ x,
                                                  const float* __restrict__ gamma,
                                                  const float* __restrict__ beta,
                                                  u16* __restrict__ xnt) {
  int bg = blockIdx.x;
  int b = bg >> 3, g = bg & 7;
  int tid = threadIdx.x;
  const float* xg = x + ((size_t)(b * 128 + g * 16)) * 4096;  // group block is contiguous: 16*4096
  float s = 0.f, sq = 0.f;
  #pragma unroll 4
  for (int i = 0; i < 64; ++i) {
    float v = xg[tid + (i << 10)];
    s += v; sq += v * v;
  }
  #pragma unroll
  for (int off = 32; off > 0; off >>= 1) {
    s += __shfl_down(s, off);
    sq += __shfl_down(sq, off);
  }
  __shared__ float red[32];
  int wid = tid >> 6;
  if ((tid & 63) == 0) { red[wid] = s; red[16 + wid] = sq; }
  __syncthreads();
  if (tid == 0) {
    float ts = 0.f, tq = 0.f;
    for (int i = 0; i < 16; ++i) { ts += red[i]; tq += red[16 + i]; }
    red[0] = ts; red[16] = tq;
  }
  __syncthreads();
  float mean = red[0] * (1.f / 65536.f);
  float var  = red[16] * (1.f / 65536.f) - mean * mean;
  float rstd = rsqrtf(var + 1e-6f);
  int c_l = tid & 15;
  int c = g * 16 + c_l;
  float ga = gamma[c] * rstd;
  float be = beta[c] - mean * ga;
  u16* outb = xnt + (size_t)b * 4096 * 128 + c;
  const float* xr = x + ((size_t)(b * 128 + c)) * 4096;
  #pragma unroll 4
  for (int i = 0; i < 64; ++i) {
    int n = ((tid + (i << 10)) >> 4);
    outb[(size_t)n * 128] = f2bf(xr[n] * ga + be);
  }
}

// ---------------- QKV GEMM: w_qkv[384,128] @ xn -> q_t,k_t [B,N,C], v [B,C,N] ----
__global__ __launch_bounds__(256) void qkv_kernel(const float* __restrict__ wq,
                                                  const float* __restrict__ bq,
                                                  const u16* __restrict__ xnt,
                                                  u16* __restrict__ qt,
                                                  u16* __restrict__ kt,
                                                  u16* __restrict__ vv) {
  __shared__ char aS[16384];  // [o 0..63][c 0..127] bf16, swizzled
  __shared__ char bS[16384];  // [n 0..63][c 0..127] bf16, swizzled
  int b = blockIdx.z;
  int o0 = blockIdx.y * 64;
  int n0 = blockIdx.x * 64;
  int tid = threadIdx.x;
  #pragma unroll
  for (int i = 0; i < 8; ++i) {
    int chunk = tid + (i << 8);
    int o = chunk >> 5, cj = (chunk & 31) << 2;
    float4 f = *reinterpret_cast<const float4*>(wq + (o0 + o) * 128 + cj);
    ushort4 h4 = make_ushort4(f2bf(f.x), f2bf(f.y), f2bf(f.z), f2bf(f.w));
    *reinterpret_cast<ushort4*>(aS + ((o * 256 + cj * 2) ^ ((o & 7) << 4))) = h4;
  }
  #pragma unroll
  for (int i = 0; i < 4; ++i) {
    int chunk = tid + (i << 8);
    int n = chunk >> 4, ch = chunk & 15;
    uint4 d = *reinterpret_cast<const uint4*>(xnt + ((size_t)(b * 4096 + n0 + n)) * 128 + ch * 8);
    *reinterpret_cast<uint4*>(bS + ((n * 256 + ch * 16) ^ ((n & 7) << 4))) = d;
  }
  __syncthreads();
  int w = tid >> 6, l = tid & 63, lr = l & 15, lg = l >> 4;
  f32x4 acc[4] = {{0,0,0,0},{0,0,0,0},{0,0,0,0},{0,0,0,0}};
  int orow = 16 * w + lr;
  #pragma unroll
  for (int kc = 0; kc < 4; ++kc) {
    int c2 = (lg * 8 + 32 * kc) * 2;
    bf16x8 a = *reinterpret_cast<const bf16x8*>(aS + ((orow * 256 + c2) ^ ((orow & 7) << 4)));
    #pragma unroll
    for (int fn = 0; fn < 4; ++fn) {
      int n = lr + 16 * fn;
      bf16x8 bb = *reinterpret_cast<const bf16x8*>(bS + ((n * 256 + c2) ^ ((n & 7) << 4)));
      acc[fn] = __builtin_amdgcn_mfma_f32_16x16x32_bf16(a, bb, acc[fn], 0, 0, 0);
    }
  }
  #pragma unroll
  for (int fn = 0; fn < 4; ++fn) {
    #pragma unroll
    for (int j = 0; j < 4; ++j) {
      int o = o0 + 16 * w + lg * 4 + j;
      int n = n0 + lr + 16 * fn;
      u16 h = f2bf(acc[fn][j] + bq[o]);
      if (o < 128)      qt[((size_t)(b * 4096 + n)) * 128 + o] = h;
      else if (o < 256) kt[((size_t)(b * 4096 + n)) * 128 + (o - 128)] = h;
      else              vv[((size_t)(b * 128 + (o - 256))) * 4096 + n] = h;
    }
  }
}

// ---------------- Flash attention: q_t,k_t[B,N,C], v[B,C,N] -> h_t[B,N,C] --------
__global__ __launch_bounds__(256) void attn_kernel(const u16* __restrict__ qt,
                                                   const u16* __restrict__ kt,
                                                   const u16* __restrict__ vv,
                                                   u16* __restrict__ ht) {
  __shared__ char kS[16384];  // [kp 0..63][c 0..127] bf16 swizzled
  __shared__ char vS[16384];  // [c 0..127][k 0..63] bf16 swizzled
  __shared__ char pS[8192];   // [q 0..63][k 0..63] bf16 swizzled (per-wave rows)
  int b = blockIdx.y;
  int q0 = blockIdx.x * 64;
  int tid = threadIdx.x;
  int w = tid >> 6, l = tid & 63, lr = l & 15, lg = l >> 4;

  bf16x8 qa[4];
  {
    const u16* qrow = qt + ((size_t)(b * 4096 + q0 + 16 * w + lr)) * 128 + lg * 8;
    #pragma unroll
    for (int kc = 0; kc < 4; ++kc)
      qa[kc] = *reinterpret_cast<const bf16x8*>(qrow + 32 * kc);
  }
  f32x4 acc[8];
  #pragma unroll
  for (int i = 0; i < 8; ++i) acc[i] = (f32x4){0.f, 0.f, 0.f, 0.f};
  float m2[4], lsum[4];
  #pragma unroll
  for (int j = 0; j < 4; ++j) { m2[j] = -1e30f; lsum[j] = 0.f; }
  const float alpha = 0.08838834764831845f * 1.4426950408889634f;  // C^-0.5 * log2(e)

  for (int kti = 0; kti < 64; ++kti) {
    int kv0 = kti * 64;
    #pragma unroll
    for (int i = 0; i < 4; ++i) {
      int chunk = tid + (i << 8);
      int n = chunk >> 4, ch = chunk & 15;
      uint4 d = *reinterpret_cast<const uint4*>(kt + ((size_t)(b * 4096 + kv0 + n)) * 128 + ch * 8);
      *reinterpret_cast<uint4*>(kS + ((n * 256 + ch * 16) ^ ((n & 7) << 4))) = d;
    }
    #pragma unroll
    for (int i = 0; i < 4; ++i) {
      int chunk = tid + (i << 8);
      int c = chunk >> 3, ch = chunk & 7;
      uint4 d = *reinterpret_cast<const uint4*>(vv + ((size_t)(b * 128 + c)) * 4096 + kv0 + ch * 8);
      *reinterpret_cast<uint4*>(vS + ((c * 128 + ch * 16) ^ ((c & 7) << 4))) = d;
    }
    __syncthreads();

    // S = Q K^T  (per wave: 16 q rows x 64 k cols)
    f32x4 s[4];
    #pragma unroll
    for (int fn = 0; fn < 4; ++fn) s[fn] = (f32x4){0.f, 0.f, 0.f, 0.f};
    #pragma unroll
    for (int kc = 0; kc < 4; ++kc) {
      int c2 = (lg * 8 + 32 * kc) * 2;
      bf16x8 a = qa[kc];
      #pragma unroll
      for (int fn = 0; fn < 4; ++fn) {
        int kp = lr + 16 * fn;
        bf16x8 bb = *reinterpret_cast<const bf16x8*>(kS + ((kp * 256 + c2) ^ ((kp & 7) << 4)));
        s[fn] = __builtin_amdgcn_mfma_f32_16x16x32_bf16(a, bb, s[fn], 0, 0, 0);
      }
    }
    // online softmax (base-2 domain); row r = lg*4+j lives across the 16 lanes lr=0..15
    #pragma unroll
    for (int fn = 0; fn < 4; ++fn)
      #pragma unroll
      for (int j = 0; j < 4; ++j) s[fn][j] *= alpha;
    float mt[4];
    #pragma unroll
    for (int j = 0; j < 4; ++j)
      mt[j] = fmaxf(fmaxf(s[0][j], s[1][j]), fmaxf(s[2][j], s[3][j]));
    #pragma unroll
    for (int off = 1; off < 16; off <<= 1)
      #pragma unroll
      for (int j = 0; j < 4; ++j)
        mt[j] = fmaxf(mt[j], __shfl_xor(mt[j], off));
    float r[4], rs[4];
    #pragma unroll
    for (int j = 0; j < 4; ++j) {
      float mn = fmaxf(m2[j], mt[j]);
      r[j] = exp2f(m2[j] - mn);
      m2[j] = mn;
      rs[j] = 0.f;
    }
    #pragma unroll
    for (int fn = 0; fn < 4; ++fn)
      #pragma unroll
      for (int j = 0; j < 4; ++j) {
        float p = exp2f(s[fn][j] - m2[j]);
        s[fn][j] = p;
        rs[j] += p;
      }
    #pragma unroll
    for (int off = 1; off < 16; off <<= 1)
      #pragma unroll
      for (int j = 0; j < 4; ++j)
        rs[j] += __shfl_xor(rs[j], off);
    #pragma unroll
    for (int j = 0; j < 4; ++j) lsum[j] = lsum[j] * r[j] + rs[j];
    #pragma unroll
    for (int fc = 0; fc < 8; ++fc)
      #pragma unroll
      for (int j = 0; j < 4; ++j) acc[fc][j] *= r[j];
    // P -> LDS (bf16), per-wave private rows
    #pragma unroll
    for (int fn = 0; fn < 4; ++fn)
      #pragma unroll
      for (int j = 0; j < 4; ++j) {
        int qg = 16 * w + lg * 4 + j;
        int kp = lr + 16 * fn;
        *reinterpret_cast<u16*>(pS + ((qg * 128 + kp * 2) ^ ((qg & 7) << 4))) = f2bf(s[fn][j]);
      }
    // PV: acc[q, c] += P[q, k] * V[c, k]
    #pragma unroll
    for (int kc = 0; kc < 2; ++kc) {
      int qg = 16 * w + lr;
      int k2 = (lg * 8 + 32 * kc) * 2;
      bf16x8 pa = *reinterpret_cast<const bf16x8*>(pS + ((qg * 128 + k2) ^ ((qg & 7) << 4)));
      #pragma unroll
      for (int fc = 0; fc < 8; ++fc) {
        int c = lr + 16 * fc;
        bf16x8 vb = *reinterpret_cast<const bf16x8*>(vS + ((c * 128 + k2) ^ ((c & 7) << 4)));
        acc[fc] = __builtin_amdgcn_mfma_f32_16x16x32_bf16(pa, vb, acc[fc], 0, 0, 0);
      }
    }
    __syncthreads();
  }
  #pragma unroll
  for (int j = 0; j < 4; ++j) {
    float inv = 1.f / lsum[j];
    int qg = q0 + 16 * w + lg * 4 + j;
    u16* orow = ht + ((size_t)(b * 4096 + qg)) * 128 + lr;
    #pragma unroll
    for (int fc = 0; fc < 8; ++fc)
      orow[16 * fc] = f2bf(acc[fc][j] * inv);
  }
}

// ---------------- Proj GEMM + bias + residual: out = x + w_proj @ h ----------------
__global__ __launch_bounds__(256) void proj_kernel(const float* __restrict__ wp,
                                                   const float* __restrict__ bp,
                                                   const u16* __restrict__ ht,
                                                   const float* __restrict__ x,
                                                   float* __restrict__ out) {
  __shared__ char aS[16384];
  __shared__ char bS[16384];
  int b = blockIdx.z;
  int o0 = blockIdx.y * 64;
  int n0 = blockIdx.x * 64;
  int tid = threadIdx.x;
  #pragma unroll
  for (int i = 0; i < 8; ++i) {
    int chunk = tid + (i << 8);
    int o = chunk >> 5, cj = (chunk & 31) << 2;
    float4 f = *reinterpret_cast<const float4*>(wp + (o0 + o) * 128 + cj);
    ushort4 h4 = make_ushort4(f2bf(f.x), f2bf(f.y), f2bf(f.z), f2bf(f.w));
    *reinterpret_cast<ushort4*>(aS + ((o * 256 + cj * 2) ^ ((o & 7) << 4))) = h4;
  }
  #pragma unroll
  for (int i = 0; i < 4; ++i) {
    int chunk = tid + (i << 8);
    int n = chunk >> 4, ch = chunk & 15;
    uint4 d = *reinterpret_cast<const uint4*>(ht + ((size_t)(b * 4096 + n0 + n)) * 128 + ch * 8);
    *reinterpret_cast<uint4*>(bS + ((n * 256 + ch * 16) ^ ((n & 7) << 4))) = d;
  }
  __syncthreads();
  int w = tid >> 6, l = tid & 63, lr = l & 15, lg = l >> 4;
  f32x4 acc[4] = {{0,0,0,0},{0,0,0,0},{0,0,0,0},{0,0,0,0}};
  int orow = 16 * w + lr;
  #pragma unroll
  for (int kc = 0; kc < 4; ++kc) {
    int c2 = (lg * 8 + 32 * kc) * 2;
    bf16x8 a = *reinterpret_cast<const bf16x8*>(aS + ((orow * 256 + c2) ^ ((orow & 7) << 4)));
    #pragma unroll
    for (int fn = 0; fn < 4; ++fn) {
      int n = lr + 16 * fn;
      bf16x8 bb = *reinterpret_cast<const bf16x8*>(bS + ((n * 256 + c2) ^ ((n & 7) << 4)));
      acc[fn] = __builtin_amdgcn_mfma_f32_16x16x32_bf16(a, bb, acc[fn], 0, 0, 0);
    }
  }
  #pragma unroll
  for (int fn = 0; fn < 4; ++fn) {
    #pragma unroll
    for (int j = 0; j < 4; ++j) {
      int o = o0 + 16 * w + lg * 4 + j;
      int n = n0 + lr + 16 * fn;
      size_t idx = ((size_t)(b * 128 + o)) * 4096 + n;
      out[idx] = acc[fn][j] + bp[o] + x[idx];
    }
  }
}

extern "C" void kernel_launch(void* const* d_in, const int* in_sizes, int n_in,
                              void* d_out, int out_size, void* d_ws, size_t ws_size,
                              hipStream_t stream) {
  const float* x      = (const float*)d_in[0];
  const float* gamma  = (const float*)d_in[1];
  const float* beta   = (const float*)d_in[2];
  const float* w_qkv  = (const float*)d_in[3];
  const float* b_qkv  = (const float*)d_in[4];
  const float* w_proj = (const float*)d_in[5];
  const float* b_proj = (const float*)d_in[6];
  float* out = (float*)d_out;

  char* ws = (char*)d_ws;
  u16* xnt = (u16*)(ws);               // 4 MB, [B,N,C] bf16; reused as h_t after QKV
  u16* qt  = (u16*)(ws + (4u << 20));  // 4 MB, [B,N,C]
  u16* kt  = (u16*)(ws + (8u << 20));  // 4 MB, [B,N,C]
  u16* vv  = (u16*)(ws + (12u << 20)); // 4 MB, [B,C,N]
  u16* ht  = xnt;                      // alias: xn dead after qkv_kernel

  hipLaunchKernelGGL(gn_kernel, dim3(32), dim3(1024), 0, stream, x, gamma, beta, xnt);
  hipLaunchKernelGGL(qkv_kernel, dim3(64, 6, 4), dim3(256), 0, stream, w_qkv, b_qkv, xnt, qt, kt, vv);
  hipLaunchKernelGGL(attn_kernel, dim3(64, 4), dim3(256), 0, stream, qt, kt, vv, ht);
  hipLaunchKernelGGL(proj_kernel, dim3(64, 2, 4), dim3(256), 0, stream, w_proj, b_proj, ht, x, out);
}

// Round 3
// 198.519 us; speedup vs baseline: 1.3971x; 1.3971x over previous
//
#include <hip/hip_runtime.h>

typedef __bf16 bf16_t;
typedef bf16_t bf16x8 __attribute__((ext_vector_type(8)));
typedef float f32x4 __attribute__((ext_vector_type(4)));
typedef unsigned short u16;
typedef unsigned int u32;

__device__ __forceinline__ u16 f2bf(float f) {
  union { float f; u32 u; } v; v.f = f;
  u32 r = v.u + 0x7fffu + ((v.u >> 16) & 1u);
  return (u16)(r >> 16);
}

// ---------------- GroupNorm stats: partial sums per (b,g,chunk) -----------------
// grid 512 = 32 (b,g) x 16 chunks; block reduces 4096 contiguous floats
__global__ __launch_bounds__(256) void gn_stats(const float* __restrict__ x,
                                                float* __restrict__ partial) {
  int bg = blockIdx.x >> 4, ck = blockIdx.x & 15;
  int tid = threadIdx.x;
  const float4* base = reinterpret_cast<const float4*>(x + (size_t)bg * 65536 + ck * 4096);
  float s = 0.f, sq = 0.f;
  #pragma unroll
  for (int j = 0; j < 4; ++j) {
    float4 v = base[j * 256 + tid];
    s += v.x + v.y + v.z + v.w;
    sq += v.x * v.x + v.y * v.y + v.z * v.z + v.w * v.w;
  }
  #pragma unroll
  for (int off = 32; off > 0; off >>= 1) {
    s += __shfl_down(s, off);
    sq += __shfl_down(sq, off);
  }
  __shared__ float red[8];
  int wid = tid >> 6;
  if ((tid & 63) == 0) { red[wid] = s; red[4 + wid] = sq; }
  __syncthreads();
  if (tid == 0) {
    float ts = red[0] + red[1] + red[2] + red[3];
    float tq = red[4] + red[5] + red[6] + red[7];
    partial[(bg * 16 + ck) * 2] = ts;
    partial[(bg * 16 + ck) * 2 + 1] = tq;
  }
}

// ---------------- GroupNorm normalize: x -> xn_t[B,N,C] bf16 --------------------
// grid 512 = 32 (b,g) x 16 n-chunks of 256
__global__ __launch_bounds__(256) void gn_norm(const float* __restrict__ x,
                                               const float* __restrict__ gamma,
                                               const float* __restrict__ beta,
                                               const float* __restrict__ partial,
                                               u16* __restrict__ xnt) {
  int bg = blockIdx.x >> 4, ck = blockIdx.x & 15;
  int b = bg >> 3, g = bg & 7;
  int tid = threadIdx.x;
  float s = 0.f, sq = 0.f;
  #pragma unroll
  for (int k = 0; k < 16; ++k) {
    s += partial[(bg * 16 + k) * 2];
    sq += partial[(bg * 16 + k) * 2 + 1];
  }
  float mean = s * (1.f / 65536.f);
  float var = sq * (1.f / 65536.f) - mean * mean;
  float rstd = rsqrtf(var + 1e-6f);
  int c_l = tid & 15;
  int c = g * 16 + c_l;
  float ga = gamma[c] * rstd;
  float be = beta[c] - mean * ga;
  const float* xr = x + ((size_t)(b * 128 + c)) * 4096;
  u16* outb = xnt + (size_t)b * 4096 * 128 + c;
  int n0 = ck * 256 + (tid >> 4);
  #pragma unroll
  for (int i = 0; i < 16; ++i) {
    int n = n0 + i * 16;
    outb[(size_t)n * 128] = f2bf(xr[n] * ga + be);
  }
}

// ---------------- QKV GEMM: w_qkv[384,128] @ xn -> q_t,k_t [B,N,C], v [B,C,N] ----
__global__ __launch_bounds__(256) void qkv_kernel(const float* __restrict__ wq,
                                                  const float* __restrict__ bq,
                                                  const u16* __restrict__ xnt,
                                                  u16* __restrict__ qt,
                                                  u16* __restrict__ kt,
                                                  u16* __restrict__ vv) {
  __shared__ char aS[16384];  // [o 0..63][c 0..127] bf16, swizzled
  __shared__ char bS[16384];  // [n 0..63][c 0..127] bf16, swizzled
  int b = blockIdx.z;
  int o0 = blockIdx.y * 64;
  int n0 = blockIdx.x * 64;
  int tid = threadIdx.x;
  #pragma unroll
  for (int i = 0; i < 8; ++i) {
    int chunk = tid + (i << 8);
    int o = chunk >> 5, cj = (chunk & 31) << 2;
    float4 f = *reinterpret_cast<const float4*>(wq + (o0 + o) * 128 + cj);
    ushort4 h4 = make_ushort4(f2bf(f.x), f2bf(f.y), f2bf(f.z), f2bf(f.w));
    *reinterpret_cast<ushort4*>(aS + ((o * 256 + cj * 2) ^ ((o & 7) << 4))) = h4;
  }
  #pragma unroll
  for (int i = 0; i < 4; ++i) {
    int chunk = tid + (i << 8);
    int n = chunk >> 4, ch = chunk & 15;
    uint4 d = *reinterpret_cast<const uint4*>(xnt + ((size_t)(b * 4096 + n0 + n)) * 128 + ch * 8);
    *reinterpret_cast<uint4*>(bS + ((n * 256 + ch * 16) ^ ((n & 7) << 4))) = d;
  }
  __syncthreads();
  int w = tid >> 6, l = tid & 63, lr = l & 15, lg = l >> 4;
  f32x4 acc[4] = {{0,0,0,0},{0,0,0,0},{0,0,0,0},{0,0,0,0}};
  int orow = 16 * w + lr;
  #pragma unroll
  for (int kc = 0; kc < 4; ++kc) {
    int c2 = (lg * 8 + 32 * kc) * 2;
    bf16x8 a = *reinterpret_cast<const bf16x8*>(aS + ((orow * 256 + c2) ^ ((orow & 7) << 4)));
    #pragma unroll
    for (int fn = 0; fn < 4; ++fn) {
      int n = lr + 16 * fn;
      bf16x8 bb = *reinterpret_cast<const bf16x8*>(bS + ((n * 256 + c2) ^ ((n & 7) << 4)));
      acc[fn] = __builtin_amdgcn_mfma_f32_16x16x32_bf16(a, bb, acc[fn], 0, 0, 0);
    }
  }
  #pragma unroll
  for (int fn = 0; fn < 4; ++fn) {
    #pragma unroll
    for (int j = 0; j < 4; ++j) {
      int o = o0 + 16 * w + lg * 4 + j;
      int n = n0 + lr + 16 * fn;
      u16 h = f2bf(acc[fn][j] + bq[o]);
      if (o < 128)      qt[((size_t)(b * 4096 + n)) * 128 + o] = h;
      else if (o < 256) kt[((size_t)(b * 4096 + n)) * 128 + (o - 128)] = h;
      else              vv[((size_t)(b * 128 + (o - 256))) * 4096 + n] = h;
    }
  }
}

// ---- Flash attention, split-KV: writes unnormalized f32 partials + (m,l) -------
// grid (64 q-tiles, 4 kv-splits, 4 b); each block: 16 KV iters of 64
__global__ __launch_bounds__(256) void attn_kernel(const u16* __restrict__ qt,
                                                   const u16* __restrict__ kt,
                                                   const u16* __restrict__ vv,
                                                   float* __restrict__ opart,
                                                   float* __restrict__ ml) {
  __shared__ char kS[16384];  // [kp 0..63][c 0..127] bf16 swizzled
  __shared__ char vS[16384];  // [c 0..127][k 0..63] bf16 swizzled
  __shared__ char pS[8192];   // [q 0..63][k 0..63] bf16 swizzled (per-wave rows)
  int b = blockIdx.z;
  int sp = blockIdx.y;
  int q0 = blockIdx.x * 64;
  int tid = threadIdx.x;
  int w = tid >> 6, l = tid & 63, lr = l & 15, lg = l >> 4;

  bf16x8 qa[4];
  {
    const u16* qrow = qt + ((size_t)(b * 4096 + q0 + 16 * w + lr)) * 128 + lg * 8;
    #pragma unroll
    for (int kc = 0; kc < 4; ++kc)
      qa[kc] = *reinterpret_cast<const bf16x8*>(qrow + 32 * kc);
  }
  f32x4 acc[8];
  #pragma unroll
  for (int i = 0; i < 8; ++i) acc[i] = (f32x4){0.f, 0.f, 0.f, 0.f};
  float m2[4], lsum[4];
  #pragma unroll
  for (int j = 0; j < 4; ++j) { m2[j] = -1e30f; lsum[j] = 0.f; }
  const float alpha = 0.08838834764831845f * 1.4426950408889634f;  // C^-0.5 * log2(e)

  for (int kti = 0; kti < 16; ++kti) {
    int kv0 = (sp * 16 + kti) * 64;
    #pragma unroll
    for (int i = 0; i < 4; ++i) {
      int chunk = tid + (i << 8);
      int n = chunk >> 4, ch = chunk & 15;
      uint4 d = *reinterpret_cast<const uint4*>(kt + ((size_t)(b * 4096 + kv0 + n)) * 128 + ch * 8);
      *reinterpret_cast<uint4*>(kS + ((n * 256 + ch * 16) ^ ((n & 7) << 4))) = d;
    }
    #pragma unroll
    for (int i = 0; i < 4; ++i) {
      int chunk = tid + (i << 8);
      int c = chunk >> 3, ch = chunk & 7;
      uint4 d = *reinterpret_cast<const uint4*>(vv + ((size_t)(b * 128 + c)) * 4096 + kv0 + ch * 8);
      *reinterpret_cast<uint4*>(vS + ((c * 128 + ch * 16) ^ ((c & 7) << 4))) = d;
    }
    __syncthreads();

    // S = Q K^T  (per wave: 16 q rows x 64 k cols)
    f32x4 s[4];
    #pragma unroll
    for (int fn = 0; fn < 4; ++fn) s[fn] = (f32x4){0.f, 0.f, 0.f, 0.f};
    #pragma unroll
    for (int kc = 0; kc < 4; ++kc) {
      int c2 = (lg * 8 + 32 * kc) * 2;
      bf16x8 a = qa[kc];
      #pragma unroll
      for (int fn = 0; fn < 4; ++fn) {
        int kp = lr + 16 * fn;
        bf16x8 bb = *reinterpret_cast<const bf16x8*>(kS + ((kp * 256 + c2) ^ ((kp & 7) << 4)));
        s[fn] = __builtin_amdgcn_mfma_f32_16x16x32_bf16(a, bb, s[fn], 0, 0, 0);
      }
    }
    // online softmax (base-2 domain); row r = lg*4+j lives across lanes lr=0..15
    #pragma unroll
    for (int fn = 0; fn < 4; ++fn)
      #pragma unroll
      for (int j = 0; j < 4; ++j) s[fn][j] *= alpha;
    float mt[4];
    #pragma unroll
    for (int j = 0; j < 4; ++j)
      mt[j] = fmaxf(fmaxf(s[0][j], s[1][j]), fmaxf(s[2][j], s[3][j]));
    #pragma unroll
    for (int off = 1; off < 16; off <<= 1)
      #pragma unroll
      for (int j = 0; j < 4; ++j)
        mt[j] = fmaxf(mt[j], __shfl_xor(mt[j], off));
    float r[4], rs[4];
    #pragma unroll
    for (int j = 0; j < 4; ++j) {
      float mn = fmaxf(m2[j], mt[j]);
      r[j] = exp2f(m2[j] - mn);
      m2[j] = mn;
      rs[j] = 0.f;
    }
    #pragma unroll
    for (int fn = 0; fn < 4; ++fn)
      #pragma unroll
      for (int j = 0; j < 4; ++j) {
        float p = exp2f(s[fn][j] - m2[j]);
        s[fn][j] = p;
        rs[j] += p;
      }
    #pragma unroll
    for (int off = 1; off < 16; off <<= 1)
      #pragma unroll
      for (int j = 0; j < 4; ++j)
        rs[j] += __shfl_xor(rs[j], off);
    #pragma unroll
    for (int j = 0; j < 4; ++j) lsum[j] = lsum[j] * r[j] + rs[j];
    #pragma unroll
    for (int fc = 0; fc < 8; ++fc)
      #pragma unroll
      for (int j = 0; j < 4; ++j) acc[fc][j] *= r[j];
    // P -> LDS (bf16), per-wave private rows
    #pragma unroll
    for (int fn = 0; fn < 4; ++fn)
      #pragma unroll
      for (int j = 0; j < 4; ++j) {
        int qg = 16 * w + lg * 4 + j;
        int kp = lr + 16 * fn;
        *reinterpret_cast<u16*>(pS + ((qg * 128 + kp * 2) ^ ((qg & 7) << 4))) = f2bf(s[fn][j]);
      }
    // PV: acc[q, c] += P[q, k] * V[c, k]
    #pragma unroll
    for (int kc = 0; kc < 2; ++kc) {
      int qg = 16 * w + lr;
      int k2 = (lg * 8 + 32 * kc) * 2;
      bf16x8 pa = *reinterpret_cast<const bf16x8*>(pS + ((qg * 128 + k2) ^ ((qg & 7) << 4)));
      #pragma unroll
      for (int fc = 0; fc < 8; ++fc) {
        int c = lr + 16 * fc;
        bf16x8 vb = *reinterpret_cast<const bf16x8*>(vS + ((c * 128 + k2) ^ ((c & 7) << 4)));
        acc[fc] = __builtin_amdgcn_mfma_f32_16x16x32_bf16(pa, vb, acc[fc], 0, 0, 0);
      }
    }
    __syncthreads();
  }
  // write unnormalized partial O (f32) + per-row (m, l)
  #pragma unroll
  for (int j = 0; j < 4; ++j) {
    int nloc = 16 * w + lg * 4 + j;
    size_t row = (size_t)(sp * 16384 + b * 4096 + q0 + nloc);
    float* orow = opart + row * 128 + lr;
    #pragma unroll
    for (int fc = 0; fc < 8; ++fc)
      orow[16 * fc] = acc[fc][j];
    if (lr == 0) {
      ml[row * 2] = m2[j];
      ml[row * 2 + 1] = lsum[j];
    }
  }
}

// ---------------- Merge splits -> ht[B,N,C] bf16 --------------------------------
// grid 256 blocks x 256 thr; wave = one row per iter, lane = 2 channels
__global__ __launch_bounds__(256) void merge_kernel(const float* __restrict__ opart,
                                                    const float* __restrict__ ml,
                                                    u16* __restrict__ ht) {
  int tid = threadIdx.x;
  int c2 = (tid & 63) * 2;
  int rw = tid >> 6;  // wave id 0..3
  int bn0 = blockIdx.x * 64;
  for (int i = 0; i < 16; ++i) {
    int bn = bn0 + i * 4 + rw;
    float m[4], lv[4];
    #pragma unroll
    for (int s = 0; s < 4; ++s) {
      m[s] = ml[((size_t)(s * 16384 + bn)) * 2];
      lv[s] = ml[((size_t)(s * 16384 + bn)) * 2 + 1];
    }
    float M = fmaxf(fmaxf(m[0], m[1]), fmaxf(m[2], m[3]));
    float wgt[4], L = 0.f;
    #pragma unroll
    for (int s = 0; s < 4; ++s) {
      wgt[s] = exp2f(m[s] - M);
      L += wgt[s] * lv[s];
    }
    float inv = 1.f / L;
    float ox = 0.f, oy = 0.f;
    #pragma unroll
    for (int s = 0; s < 4; ++s) {
      const float* p = opart + ((size_t)(s * 16384 + bn)) * 128 + c2;
      ox += wgt[s] * p[0];
      oy += wgt[s] * p[1];
    }
    u32 pair = (u32)f2bf(ox * inv) | ((u32)f2bf(oy * inv) << 16);
    *reinterpret_cast<u32*>(ht + ((size_t)bn) * 128 + c2) = pair;
  }
}

// ---------------- Proj GEMM + bias + residual: out = x + w_proj @ h ----------------
__global__ __launch_bounds__(256) void proj_kernel(const float* __restrict__ wp,
                                                   const float* __restrict__ bp,
                                                   const u16* __restrict__ ht,
                                                   const float* __restrict__ x,
                                                   float* __restrict__ out) {
  __shared__ char aS[16384];
  __shared__ char bS[16384];
  int b = blockIdx.z;
  int o0 = blockIdx.y * 64;
  int n0 = blockIdx.x * 64;
  int tid = threadIdx.x;
  #pragma unroll
  for (int i = 0; i < 8; ++i) {
    int chunk = tid + (i << 8);
    int o = chunk >> 5, cj = (chunk & 31) << 2;
    float4 f = *reinterpret_cast<const float4*>(wp + (o0 + o) * 128 + cj);
    ushort4 h4 = make_ushort4(f2bf(f.x), f2bf(f.y), f2bf(f.z), f2bf(f.w));
    *reinterpret_cast<ushort4*>(aS + ((o * 256 + cj * 2) ^ ((o & 7) << 4))) = h4;
  }
  #pragma unroll
  for (int i = 0; i < 4; ++i) {
    int chunk = tid + (i << 8);
    int n = chunk >> 4, ch = chunk & 15;
    uint4 d = *reinterpret_cast<const uint4*>(ht + ((size_t)(b * 4096 + n0 + n)) * 128 + ch * 8);
    *reinterpret_cast<uint4*>(bS + ((n * 256 + ch * 16) ^ ((n & 7) << 4))) = d;
  }
  __syncthreads();
  int w = tid >> 6, l = tid & 63, lr = l & 15, lg = l >> 4;
  f32x4 acc[4] = {{0,0,0,0},{0,0,0,0},{0,0,0,0},{0,0,0,0}};
  int orow = 16 * w + lr;
  #pragma unroll
  for (int kc = 0; kc < 4; ++kc) {
    int c2 = (lg * 8 + 32 * kc) * 2;
    bf16x8 a = *reinterpret_cast<const bf16x8*>(aS + ((orow * 256 + c2) ^ ((orow & 7) << 4)));
    #pragma unroll
    for (int fn = 0; fn < 4; ++fn) {
      int n = lr + 16 * fn;
      bf16x8 bb = *reinterpret_cast<const bf16x8*>(bS + ((n * 256 + c2) ^ ((n & 7) << 4)));
      acc[fn] = __builtin_amdgcn_mfma_f32_16x16x32_bf16(a, bb, acc[fn], 0, 0, 0);
    }
  }
  #pragma unroll
  for (int fn = 0; fn < 4; ++fn) {
    #pragma unroll
    for (int j = 0; j < 4; ++j) {
      int o = o0 + 16 * w + lg * 4 + j;
      int n = n0 + lr + 16 * fn;
      size_t idx = ((size_t)(b * 128 + o)) * 4096 + n;
      out[idx] = acc[fn][j] + bp[o] + x[idx];
    }
  }
}

extern "C" void kernel_launch(void* const* d_in, const int* in_sizes, int n_in,
                              void* d_out, int out_size, void* d_ws, size_t ws_size,
                              hipStream_t stream) {
  const float* x      = (const float*)d_in[0];
  const float* gamma  = (const float*)d_in[1];
  const float* beta   = (const float*)d_in[2];
  const float* w_qkv  = (const float*)d_in[3];
  const float* b_qkv  = (const float*)d_in[4];
  const float* w_proj = (const float*)d_in[5];
  const float* b_proj = (const float*)d_in[6];
  float* out = (float*)d_out;

  char* ws = (char*)d_ws;
  u16* xnt   = (u16*)(ws);               // 4 MB, [B,N,C] bf16; reused as h_t
  u16* qt    = (u16*)(ws + (4u << 20));  // 4 MB, [B,N,C]
  u16* kt    = (u16*)(ws + (8u << 20));  // 4 MB, [B,N,C]
  u16* vv    = (u16*)(ws + (12u << 20)); // 4 MB, [B,C,N]
  float* opart = (float*)(ws + (16u << 20)); // 32 MB, [4 splits][B*N][C] f32
  float* ml    = (float*)(ws + (48u << 20)); // 512 KB, [4 splits][B*N][2] f32
  float* parts = (float*)(ws + (49u << 20)); // 4 KB, GN partial sums [32][16][2]
  u16* ht = xnt;

  hipLaunchKernelGGL(gn_stats, dim3(512), dim3(256), 0, stream, x, parts);
  hipLaunchKernelGGL(gn_norm, dim3(512), dim3(256), 0, stream, x, gamma, beta, parts, xnt);
  hipLaunchKernelGGL(qkv_kernel, dim3(64, 6, 4), dim3(256), 0, stream, w_qkv, b_qkv, xnt, qt, kt, vv);
  hipLaunchKernelGGL(attn_kernel, dim3(64, 4, 4), dim3(256), 0, stream, qt, kt, vv, opart, ml);
  hipLaunchKernelGGL(merge_kernel, dim3(256), dim3(256), 0, stream, opart, ml, ht);
  hipLaunchKernelGGL(proj_kernel, dim3(64, 2, 4), dim3(256), 0, stream, w_proj, b_proj, ht, x, out);
}

// Round 5
// 186.706 us; speedup vs baseline: 1.4855x; 1.0633x over previous
//
#include <hip/hip_runtime.h>

typedef __bf16 bf16_t;
typedef bf16_t bf16x8 __attribute__((ext_vector_type(8)));
typedef float f32x4 __attribute__((ext_vector_type(4)));
typedef unsigned short u16;
typedef unsigned int u32;

__device__ __forceinline__ u16 f2bf(float f) {
  union { float f; u32 u; } v; v.f = f;
  u32 r = v.u + 0x7fffu + ((v.u >> 16) & 1u);
  return (u16)(r >> 16);
}
__device__ __forceinline__ float bfu2f(u32 h) {
  union { u32 u; float f; } v; v.u = h << 16;
  return v.f;
}
// global -> LDS direct 16B load; LDS dest must be wave-uniform base + lane*16
__device__ __forceinline__ void gll16(const void* g, void* l) {
  __builtin_amdgcn_global_load_lds((const __attribute__((address_space(1))) unsigned int*)g,
                                   (__attribute__((address_space(3))) unsigned int*)l, 16, 0, 0);
}

// ---------------- GroupNorm stats: partial sums per (b,g,chunk) -----------------
__global__ __launch_bounds__(256) void gn_stats(const float* __restrict__ x,
                                                float* __restrict__ partial) {
  int bg = blockIdx.x >> 4, ck = blockIdx.x & 15;
  int tid = threadIdx.x;
  const float4* base = reinterpret_cast<const float4*>(x + (size_t)bg * 65536 + ck * 4096);
  float s = 0.f, sq = 0.f;
  #pragma unroll
  for (int j = 0; j < 4; ++j) {
    float4 v = base[j * 256 + tid];
    s += v.x + v.y + v.z + v.w;
    sq += v.x * v.x + v.y * v.y + v.z * v.z + v.w * v.w;
  }
  #pragma unroll
  for (int off = 32; off > 0; off >>= 1) {
    s += __shfl_down(s, off);
    sq += __shfl_down(sq, off);
  }
  __shared__ float red[8];
  int wid = tid >> 6;
  if ((tid & 63) == 0) { red[wid] = s; red[4 + wid] = sq; }
  __syncthreads();
  if (tid == 0) {
    float ts = red[0] + red[1] + red[2] + red[3];
    float tq = red[4] + red[5] + red[6] + red[7];
    partial[(bg * 16 + ck) * 2] = ts;
    partial[(bg * 16 + ck) * 2 + 1] = tq;
  }
}

// ---------------- GroupNorm normalize: x -> xn_t[B,N,C] bf16 --------------------
__global__ __launch_bounds__(256) void gn_norm(const float* __restrict__ x,
                                               const float* __restrict__ gamma,
                                               const float* __restrict__ beta,
                                               const float* __restrict__ partial,
                                               u16* __restrict__ xnt) {
  int bg = blockIdx.x >> 4, ck = blockIdx.x & 15;
  int b = bg >> 3, g = bg & 7;
  int tid = threadIdx.x;
  float s = 0.f, sq = 0.f;
  #pragma unroll
  for (int k = 0; k < 16; ++k) {
    s += partial[(bg * 16 + k) * 2];
    sq += partial[(bg * 16 + k) * 2 + 1];
  }
  float mean = s * (1.f / 65536.f);
  float var = sq * (1.f / 65536.f) - mean * mean;
  float rstd = rsqrtf(var + 1e-6f);
  int c_l = tid & 15;
  int c = g * 16 + c_l;
  float ga = gamma[c] * rstd;
  float be = beta[c] - mean * ga;
  const float* xr = x + ((size_t)(b * 128 + c)) * 4096;
  u16* outb = xnt + (size_t)b * 4096 * 128 + c;
  int n0 = ck * 256 + (tid >> 4);
  #pragma unroll
  for (int i = 0; i < 16; ++i) {
    int n = n0 + i * 16;
    outb[(size_t)n * 128] = f2bf(xr[n] * ga + be);
  }
}

// ---------------- QKV GEMM: w_qkv[384,128] @ xn -> q_t,k_t [B,N,C], v [B,C,N] ----
// q is pre-scaled by alpha = C^-0.5 * log2(e) so attn softmax runs in base-2 with no per-tile mul
__global__ __launch_bounds__(256) void qkv_kernel(const float* __restrict__ wq,
                                                  const float* __restrict__ bq,
                                                  const u16* __restrict__ xnt,
                                                  u16* __restrict__ qt,
                                                  u16* __restrict__ kt,
                                                  u16* __restrict__ vv) {
  __shared__ char aS[16384];  // [o 0..63][c 0..127] bf16, swizzled
  __shared__ char bS[16384];  // [n 0..63][c 0..127] bf16, swizzled
  int b = blockIdx.z;
  int o0 = blockIdx.y * 64;
  int n0 = blockIdx.x * 64;
  int tid = threadIdx.x;
  #pragma unroll
  for (int i = 0; i < 8; ++i) {
    int chunk = tid + (i << 8);
    int o = chunk >> 5, cj = (chunk & 31) << 2;
    float4 f = *reinterpret_cast<const float4*>(wq + (o0 + o) * 128 + cj);
    ushort4 h4 = make_ushort4(f2bf(f.x), f2bf(f.y), f2bf(f.z), f2bf(f.w));
    *reinterpret_cast<ushort4*>(aS + ((o * 256 + cj * 2) ^ ((o & 7) << 4))) = h4;
  }
  #pragma unroll
  for (int i = 0; i < 4; ++i) {
    int chunk = tid + (i << 8);
    int n = chunk >> 4, ch = chunk & 15;
    uint4 d = *reinterpret_cast<const uint4*>(xnt + ((size_t)(b * 4096 + n0 + n)) * 128 + ch * 8);
    *reinterpret_cast<uint4*>(bS + ((n * 256 + ch * 16) ^ ((n & 7) << 4))) = d;
  }
  __syncthreads();
  int w = tid >> 6, l = tid & 63, lr = l & 15, lg = l >> 4;
  f32x4 acc[4] = {{0,0,0,0},{0,0,0,0},{0,0,0,0},{0,0,0,0}};
  int orow = 16 * w + lr;
  #pragma unroll
  for (int kc = 0; kc < 4; ++kc) {
    int c2 = (lg * 8 + 32 * kc) * 2;
    bf16x8 a = *reinterpret_cast<const bf16x8*>(aS + ((orow * 256 + c2) ^ ((orow & 7) << 4)));
    #pragma unroll
    for (int fn = 0; fn < 4; ++fn) {
      int n = lr + 16 * fn;
      bf16x8 bb = *reinterpret_cast<const bf16x8*>(bS + ((n * 256 + c2) ^ ((n & 7) << 4)));
      acc[fn] = __builtin_amdgcn_mfma_f32_16x16x32_bf16(a, bb, acc[fn], 0, 0, 0);
    }
  }
  const float alpha = 0.12753325f;  // 128^-0.5 * log2(e)
  #pragma unroll
  for (int fn = 0; fn < 4; ++fn) {
    #pragma unroll
    for (int j = 0; j < 4; ++j) {
      int o = o0 + 16 * w + lg * 4 + j;
      int n = n0 + lr + 16 * fn;
      float v = acc[fn][j] + bq[o];
      if (o < 128)      qt[((size_t)(b * 4096 + n)) * 128 + o] = f2bf(v * alpha);
      else if (o < 256) kt[((size_t)(b * 4096 + n)) * 128 + (o - 128)] = f2bf(v);
      else              vv[((size_t)(b * 128 + (o - 256))) * 4096 + n] = f2bf(v);
    }
  }
}

// ---- Flash attention, split-KV: writes unnormalized bf16 partials + (m,l) f32 ----
// grid (64 q-tiles, 4 kv-splits, 4 b); each block: 16 KV iters of 64
__global__ __launch_bounds__(256) void attn_kernel(const u16* __restrict__ qt,
                                                   const u16* __restrict__ kt,
                                                   const u16* __restrict__ vv,
                                                   u16* __restrict__ opart,
                                                   float* __restrict__ ml) {
  __shared__ char kS[16384];  // [kp 0..63][c 0..127] bf16 swizzled
  __shared__ char vS[16384];  // [c 0..127][k 0..63] bf16 swizzled
  __shared__ char pS[8192];   // [q 0..63][k 0..63] bf16 swizzled (per-wave rows)
  int b = blockIdx.z;
  int sp = blockIdx.y;
  int q0 = blockIdx.x * 64;
  int tid = threadIdx.x;
  int w = tid >> 6, l = tid & 63, lr = l & 15, lg = l >> 4;

  bf16x8 qa[4];
  {
    const u16* qrow = qt + ((size_t)(b * 4096 + q0 + 16 * w + lr)) * 128 + lg * 8;
    #pragma unroll
    for (int kc = 0; kc < 4; ++kc)
      qa[kc] = *reinterpret_cast<const bf16x8*>(qrow + 32 * kc);
  }
  f32x4 acc[8];
  #pragma unroll
  for (int i = 0; i < 8; ++i) acc[i] = (f32x4){0.f, 0.f, 0.f, 0.f};
  float m2[4], lsum[4];
  #pragma unroll
  for (int j = 0; j < 4; ++j) { m2[j] = -1e30f; lsum[j] = 0.f; }

  for (int kti = 0; kti < 16; ++kti) {
    int kv0 = (sp * 16 + kti) * 64;
    // K tile: linear LDS fill, inverse-swizzled global source
    const u16* ktb = kt + ((size_t)(b * 4096 + kv0)) * 128;
    #pragma unroll
    for (int i = 0; i < 4; ++i) {
      int n = (tid >> 4) + i * 16;
      int ck = (tid & 15) ^ (n & 7);
      gll16(ktb + n * 128 + ck * 8, kS + tid * 16 + i * 4096);
    }
    // V tile
    const u16* vvb = vv + ((size_t)b * 128) * 4096 + kv0;
    #pragma unroll
    for (int i = 0; i < 4; ++i) {
      int c = (tid >> 3) + i * 32;
      int ck = (tid & 7) ^ (c & 7);
      gll16(vvb + (size_t)c * 4096 + ck * 8, vS + tid * 16 + i * 4096);
    }
    __syncthreads();

    // S = Q K^T  (per wave: 16 q rows x 64 k cols); alpha pre-folded into Q
    f32x4 s[4];
    #pragma unroll
    for (int fn = 0; fn < 4; ++fn) s[fn] = (f32x4){0.f, 0.f, 0.f, 0.f};
    #pragma unroll
    for (int kc = 0; kc < 4; ++kc) {
      int c2 = (lg * 8 + 32 * kc) * 2;
      bf16x8 a = qa[kc];
      #pragma unroll
      for (int fn = 0; fn < 4; ++fn) {
        int kp = lr + 16 * fn;
        bf16x8 bb = *reinterpret_cast<const bf16x8*>(kS + ((kp * 256 + c2) ^ ((kp & 7) << 4)));
        s[fn] = __builtin_amdgcn_mfma_f32_16x16x32_bf16(a, bb, s[fn], 0, 0, 0);
      }
    }
    // online softmax, base-2, defer-max (THR=8): row r=lg*4+j across lanes lr=0..15
    float mt[4];
    #pragma unroll
    for (int j = 0; j < 4; ++j)
      mt[j] = fmaxf(fmaxf(s[0][j], s[1][j]), fmaxf(s[2][j], s[3][j]));
    #pragma unroll
    for (int off = 1; off < 16; off <<= 1)
      #pragma unroll
      for (int j = 0; j < 4; ++j)
        mt[j] = fmaxf(mt[j], __shfl_xor(mt[j], off));
    bool grow = (mt[0] > m2[0] + 8.f) || (mt[1] > m2[1] + 8.f) ||
                (mt[2] > m2[2] + 8.f) || (mt[3] > m2[3] + 8.f);
    if (__any(grow)) {
      float r[4];
      #pragma unroll
      for (int j = 0; j < 4; ++j) {
        float mn = fmaxf(m2[j], mt[j]);
        r[j] = exp2f(m2[j] - mn);
        m2[j] = mn;
        lsum[j] *= r[j];
      }
      #pragma unroll
      for (int fc = 0; fc < 8; ++fc)
        #pragma unroll
        for (int j = 0; j < 4; ++j) acc[fc][j] *= r[j];
    }
    // P = exp2(S - m2); per-lane partial lsum; P -> LDS bf16 (per-wave rows)
    #pragma unroll
    for (int fn = 0; fn < 4; ++fn)
      #pragma unroll
      for (int j = 0; j < 4; ++j) {
        float p = exp2f(s[fn][j] - m2[j]);
        lsum[j] += p;
        int qg = 16 * w + lg * 4 + j;
        int kp = lr + 16 * fn;
        *reinterpret_cast<u16*>(pS + ((qg * 128 + kp * 2) ^ ((qg & 7) << 4))) = f2bf(p);
      }
    // PV: acc[q, c] += P[q, k] * V[c, k]
    #pragma unroll
    for (int kc = 0; kc < 2; ++kc) {
      int qg = 16 * w + lr;
      int k2 = (lg * 8 + 32 * kc) * 2;
      bf16x8 pa = *reinterpret_cast<const bf16x8*>(pS + ((qg * 128 + k2) ^ ((qg & 7) << 4)));
      #pragma unroll
      for (int fc = 0; fc < 8; ++fc) {
        int c = lr + 16 * fc;
        bf16x8 vb = *reinterpret_cast<const bf16x8*>(vS + ((c * 128 + k2) ^ ((c & 7) << 4)));
        acc[fc] = __builtin_amdgcn_mfma_f32_16x16x32_bf16(pa, vb, acc[fc], 0, 0, 0);
      }
    }
    __syncthreads();
  }
  // cross-lane lsum reduce (deferred to once per kernel)
  #pragma unroll
  for (int off = 1; off < 16; off <<= 1)
    #pragma unroll
    for (int j = 0; j < 4; ++j)
      lsum[j] += __shfl_xor(lsum[j], off);
  // write unnormalized partial O (bf16) + per-row (m, l)
  #pragma unroll
  for (int j = 0; j < 4; ++j) {
    int nloc = 16 * w + lg * 4 + j;
    size_t row = (size_t)(sp * 16384 + b * 4096 + q0 + nloc);
    u16* orow = opart + row * 128 + lr;
    #pragma unroll
    for (int fc = 0; fc < 8; ++fc)
      orow[16 * fc] = f2bf(acc[fc][j]);
    if (lr == 0) {
      ml[row * 2] = m2[j];
      ml[row * 2 + 1] = lsum[j];
    }
  }
}

// ---------------- Merge splits -> ht[B,N,C] bf16 --------------------------------
__global__ __launch_bounds__(256) void merge_kernel(const u16* __restrict__ opart,
                                                    const float* __restrict__ ml,
                                                    u16* __restrict__ ht) {
  int tid = threadIdx.x;
  int c2 = (tid & 63) * 2;
  int rw = tid >> 6;  // wave id 0..3
  int bn0 = blockIdx.x * 64;
  for (int i = 0; i < 16; ++i) {
    int bn = bn0 + i * 4 + rw;
    float m[4], lv[4];
    #pragma unroll
    for (int s = 0; s < 4; ++s) {
      m[s] = ml[((size_t)(s * 16384 + bn)) * 2];
      lv[s] = ml[((size_t)(s * 16384 + bn)) * 2 + 1];
    }
    float M = fmaxf(fmaxf(m[0], m[1]), fmaxf(m[2], m[3]));
    float wgt[4], L = 0.f;
    #pragma unroll
    for (int s = 0; s < 4; ++s) {
      wgt[s] = exp2f(m[s] - M);
      L += wgt[s] * lv[s];
    }
    float inv = 1.f / L;
    float ox = 0.f, oy = 0.f;
    #pragma unroll
    for (int s = 0; s < 4; ++s) {
      u32 pr = *reinterpret_cast<const u32*>(opart + ((size_t)(s * 16384 + bn)) * 128 + c2);
      ox += wgt[s] * bfu2f(pr & 0xffffu);
      oy += wgt[s] * bfu2f(pr >> 16);
    }
    u32 pair = (u32)f2bf(ox * inv) | ((u32)f2bf(oy * inv) << 16);
    *reinterpret_cast<u32*>(ht + ((size_t)bn) * 128 + c2) = pair;
  }
}

// ---------------- Proj GEMM + bias + residual: out = x + w_proj @ h ----------------
__global__ __launch_bounds__(256) void proj_kernel(const float* __restrict__ wp,
                                                   const float* __restrict__ bp,
                                                   const u16* __restrict__ ht,
                                                   const float* __restrict__ x,
                                                   float* __restrict__ out) {
  __shared__ char aS[16384];
  __shared__ char bS[16384];
  int b = blockIdx.z;
  int o0 = blockIdx.y * 64;
  int n0 = blockIdx.x * 64;
  int tid = threadIdx.x;
  #pragma unroll
  for (int i = 0; i < 8; ++i) {
    int chunk = tid + (i << 8);
    int o = chunk >> 5, cj = (chunk & 31) << 2;
    float4 f = *reinterpret_cast<const float4*>(wp + (o0 + o) * 128 + cj);
    ushort4 h4 = make_ushort4(f2bf(f.x), f2bf(f.y), f2bf(f.z), f2bf(f.w));
    *reinterpret_cast<ushort4*>(aS + ((o * 256 + cj * 2) ^ ((o & 7) << 4))) = h4;
  }
  #pragma unroll
  for (int i = 0; i < 4; ++i) {
    int chunk = tid + (i << 8);
    int n = chunk >> 4, ch = chunk & 15;
    uint4 d = *reinterpret_cast<const uint4*>(ht + ((size_t)(b * 4096 + n0 + n)) * 128 + ch * 8);
    *reinterpret_cast<uint4*>(bS + ((n * 256 + ch * 16) ^ ((n & 7) << 4))) = d;
  }
  __syncthreads();
  int w = tid >> 6, l = tid & 63, lr = l & 15, lg = l >> 4;
  f32x4 acc[4] = {{0,0,0,0},{0,0,0,0},{0,0,0,0},{0,0,0,0}};
  int orow = 16 * w + lr;
  #pragma unroll
  for (int kc = 0; kc < 4; ++kc) {
    int c2 = (lg * 8 + 32 * kc) * 2;
    bf16x8 a = *reinterpret_cast<const bf16x8*>(aS + ((orow * 256 + c2) ^ ((orow & 7) << 4)));
    #pragma unroll
    for (int fn = 0; fn < 4; ++fn) {
      int n = lr + 16 * fn;
      bf16x8 bb = *reinterpret_cast<const bf16x8*>(bS + ((n * 256 + c2) ^ ((n & 7) << 4)));
      acc[fn] = __builtin_amdgcn_mfma_f32_16x16x32_bf16(a, bb, acc[fn], 0, 0, 0);
    }
  }
  #pragma unroll
  for (int fn = 0; fn < 4; ++fn) {
    #pragma unroll
    for (int j = 0; j < 4; ++j) {
      int o = o0 + 16 * w + lg * 4 + j;
      int n = n0 + lr + 16 * fn;
      size_t idx = ((size_t)(b * 128 + o)) * 4096 + n;
      out[idx] = acc[fn][j] + bp[o] + x[idx];
    }
  }
}

extern "C" void kernel_launch(void* const* d_in, const int* in_sizes, int n_in,
                              void* d_out, int out_size, void* d_ws, size_t ws_size,
                              hipStream_t stream) {
  const float* x      = (const float*)d_in[0];
  const float* gamma  = (const float*)d_in[1];
  const float* beta   = (const float*)d_in[2];
  const float* w_qkv  = (const float*)d_in[3];
  const float* b_qkv  = (const float*)d_in[4];
  const float* w_proj = (const float*)d_in[5];
  const float* b_proj = (const float*)d_in[6];
  float* out = (float*)d_out;

  char* ws = (char*)d_ws;
  u16* xnt   = (u16*)(ws);               // 4 MB, [B,N,C] bf16; reused as h_t
  u16* qt    = (u16*)(ws + (4u << 20));  // 4 MB, [B,N,C] (pre-scaled by alpha)
  u16* kt    = (u16*)(ws + (8u << 20));  // 4 MB, [B,N,C]
  u16* vv    = (u16*)(ws + (12u << 20)); // 4 MB, [B,C,N]
  u16* opart = (u16*)(ws + (16u << 20)); // 16 MB, [4 splits][B*N][C] bf16
  float* ml    = (float*)(ws + (48u << 20)); // 512 KB, [4 splits][B*N][2] f32
  float* parts = (float*)(ws + (49u << 20)); // 4 KB, GN partial sums [32][16][2]
  u16* ht = xnt;

  hipLaunchKernelGGL(gn_stats, dim3(512), dim3(256), 0, stream, x, parts);
  hipLaunchKernelGGL(gn_norm, dim3(512), dim3(256), 0, stream, x, gamma, beta, parts, xnt);
  hipLaunchKernelGGL(qkv_kernel, dim3(64, 6, 4), dim3(256), 0, stream, w_qkv, b_qkv, xnt, qt, kt, vv);
  hipLaunchKernelGGL(attn_kernel, dim3(64, 4, 4), dim3(256), 0, stream, qt, kt, vv, opart, ml);
  hipLaunchKernelGGL(merge_kernel, dim3(256), dim3(256), 0, stream, opart, ml, ht);
  hipLaunchKernelGGL(proj_kernel, dim3(64, 2, 4), dim3(256), 0, stream, w_proj, b_proj, ht, x, out);
}

// Round 9
// 170.037 us; speedup vs baseline: 1.6311x; 1.0980x over previous
//
#include <hip/hip_runtime.h>

typedef __bf16 bf16_t;
typedef bf16_t bf16x8 __attribute__((ext_vector_type(8)));
typedef float f32x4 __attribute__((ext_vector_type(4)));
typedef unsigned short u16;
typedef unsigned int u32;

__device__ __forceinline__ float bfu2f(u32 h) {
  union { u32 u; float f; } v; v.u = h << 16;
  return v.f;
}
// global -> LDS direct 16B load; LDS dest must be wave-uniform base + lane*16
__device__ __forceinline__ void gll16(const void* g, void* l) {
  __builtin_amdgcn_global_load_lds((const __attribute__((address_space(1))) unsigned int*)g,
                                   (__attribute__((address_space(3))) unsigned int*)l, 16, 0, 0);
}

// ---------------- GroupNorm stats: partial sums per (b,g,chunk) -----------------
__global__ __launch_bounds__(256) void gn_stats(const float* __restrict__ x,
                                                float* __restrict__ partial) {
  int bg = blockIdx.x >> 4, ck = blockIdx.x & 15;
  int tid = threadIdx.x;
  const float4* base = reinterpret_cast<const float4*>(x + (size_t)bg * 65536 + ck * 4096);
  float s = 0.f, sq = 0.f;
  #pragma unroll
  for (int j = 0; j < 4; ++j) {
    float4 v = base[j * 256 + tid];
    s += v.x + v.y + v.z + v.w;
    sq += v.x * v.x + v.y * v.y + v.z * v.z + v.w * v.w;
  }
  #pragma unroll
  for (int off = 32; off > 0; off >>= 1) {
    s += __shfl_down(s, off);
    sq += __shfl_down(sq, off);
  }
  __shared__ float red[8];
  int wid = tid >> 6;
  if ((tid & 63) == 0) { red[wid] = s; red[4 + wid] = sq; }
  __syncthreads();
  if (tid == 0) {
    float ts = red[0] + red[1] + red[2] + red[3];
    float tq = red[4] + red[5] + red[6] + red[7];
    partial[(bg * 16 + ck) * 2] = ts;
    partial[(bg * 16 + ck) * 2 + 1] = tq;
  }
}

// ---------------- GroupNorm normalize: x -> xn_t[B,N,C] bf16 --------------------
__global__ __launch_bounds__(256) void gn_norm(const float* __restrict__ x,
                                               const float* __restrict__ gamma,
                                               const float* __restrict__ beta,
                                               const float* __restrict__ partial,
                                               u16* __restrict__ xnt) {
  int bg = blockIdx.x >> 4, ck = blockIdx.x & 15;
  int b = bg >> 3, g = bg & 7;
  int tid = threadIdx.x;
  float s = 0.f, sq = 0.f;
  #pragma unroll
  for (int k = 0; k < 16; ++k) {
    s += partial[(bg * 16 + k) * 2];
    sq += partial[(bg * 16 + k) * 2 + 1];
  }
  float mean = s * (1.f / 65536.f);
  float var = sq * (1.f / 65536.f) - mean * mean;
  float rstd = rsqrtf(var + 1e-6f);
  int c_l = tid & 15;
  int c = g * 16 + c_l;
  float ga = gamma[c] * rstd;
  float be = beta[c] - mean * ga;
  const float* xr = x + ((size_t)(b * 128 + c)) * 4096;
  bf16_t* outb = (bf16_t*)(xnt + (size_t)b * 4096 * 128 + c);
  int n0 = ck * 256 + (tid >> 4);
  #pragma unroll
  for (int i = 0; i < 16; ++i) {
    int n = n0 + i * 16;
    outb[(size_t)n * 128] = (bf16_t)(xr[n] * ga + be);
  }
}

// ---------------- QKV GEMM: w_qkv[384,128] @ xn -> q_t,k_t [B,N,C], v [B,C,N] ----
// q is pre-scaled by alpha = C^-0.5 * log2(e) so attn softmax runs in base-2
__global__ __launch_bounds__(256) void qkv_kernel(const float* __restrict__ wq,
                                                  const float* __restrict__ bq,
                                                  const u16* __restrict__ xnt,
                                                  u16* __restrict__ qt,
                                                  u16* __restrict__ kt,
                                                  u16* __restrict__ vv) {
  __shared__ char aS[16384];  // [o 0..63][c 0..127] bf16, swizzled
  __shared__ char bS[16384];  // [n 0..63][c 0..127] bf16, swizzled
  int b = blockIdx.z;
  int o0 = blockIdx.y * 64;
  int n0 = blockIdx.x * 64;
  int tid = threadIdx.x;
  #pragma unroll
  for (int i = 0; i < 8; ++i) {
    int chunk = tid + (i << 8);
    int o = chunk >> 5, cj = (chunk & 31) << 2;
    float4 f = *reinterpret_cast<const float4*>(wq + (o0 + o) * 128 + cj);
    u16 h0 = __builtin_bit_cast(u16, (bf16_t)f.x);
    u16 h1 = __builtin_bit_cast(u16, (bf16_t)f.y);
    u16 h2 = __builtin_bit_cast(u16, (bf16_t)f.z);
    u16 h3 = __builtin_bit_cast(u16, (bf16_t)f.w);
    ushort4 h4 = make_ushort4(h0, h1, h2, h3);
    *reinterpret_cast<ushort4*>(aS + ((o * 256 + cj * 2) ^ ((o & 7) << 4))) = h4;
  }
  #pragma unroll
  for (int i = 0; i < 4; ++i) {
    int chunk = tid + (i << 8);
    int n = chunk >> 4, ch = chunk & 15;
    uint4 d = *reinterpret_cast<const uint4*>(xnt + ((size_t)(b * 4096 + n0 + n)) * 128 + ch * 8);
    *reinterpret_cast<uint4*>(bS + ((n * 256 + ch * 16) ^ ((n & 7) << 4))) = d;
  }
  __syncthreads();
  int w = tid >> 6, l = tid & 63, lr = l & 15, lg = l >> 4;
  f32x4 acc[4] = {{0,0,0,0},{0,0,0,0},{0,0,0,0},{0,0,0,0}};
  int orow = 16 * w + lr;
  #pragma unroll
  for (int kc = 0; kc < 4; ++kc) {
    int c2 = (lg * 8 + 32 * kc) * 2;
    bf16x8 a = *reinterpret_cast<const bf16x8*>(aS + ((orow * 256 + c2) ^ ((orow & 7) << 4)));
    #pragma unroll
    for (int fn = 0; fn < 4; ++fn) {
      int n = lr + 16 * fn;
      bf16x8 bb = *reinterpret_cast<const bf16x8*>(bS + ((n * 256 + c2) ^ ((n & 7) << 4)));
      acc[fn] = __builtin_amdgcn_mfma_f32_16x16x32_bf16(a, bb, acc[fn], 0, 0, 0);
    }
  }
  const float alpha = 0.12753325f;  // 128^-0.5 * log2(e)
  #pragma unroll
  for (int fn = 0; fn < 4; ++fn) {
    #pragma unroll
    for (int j = 0; j < 4; ++j) {
      int o = o0 + 16 * w + lg * 4 + j;
      int n = n0 + lr + 16 * fn;
      float v = acc[fn][j] + bq[o];
      if (o < 128)      ((bf16_t*)qt)[((size_t)(b * 4096 + n)) * 128 + o] = (bf16_t)(v * alpha);
      else if (o < 256) ((bf16_t*)kt)[((size_t)(b * 4096 + n)) * 128 + (o - 128)] = (bf16_t)v;
      else              ((bf16_t*)vv)[((size_t)(b * 128 + (o - 256))) * 4096 + n] = (bf16_t)v;
    }
  }
}

// ---- Flash attention, split-KV, 2-phase prefetch: bf16 partials + (m,l) f32 ----
// grid (64 q-tiles, 4 kv-splits, 4 b); each block: 16 KV iters of 64
__global__ __launch_bounds__(256) void attn_kernel(const u16* __restrict__ qt,
                                                   const u16* __restrict__ kt,
                                                   const u16* __restrict__ vv,
                                                   u16* __restrict__ opart,
                                                   float* __restrict__ ml) {
  __shared__ char kS[2][16384];  // [kp 0..63][c 0..127] bf16 swizzled
  __shared__ char vS[2][16384];  // [c 0..127][k 0..63] bf16 swizzled
  __shared__ char pS[8192];      // [q 0..63][k 0..63] bf16 swizzled (per-wave rows)
  int b = blockIdx.z;
  int sp = blockIdx.y;
  int q0 = blockIdx.x * 64;
  int tid = threadIdx.x;
  int w = tid >> 6, l = tid & 63, lr = l & 15, lg = l >> 4;

  bf16x8 qa[4];
  {
    const u16* qrow = qt + ((size_t)(b * 4096 + q0 + 16 * w + lr)) * 128 + lg * 8;
    #pragma unroll
    for (int kc = 0; kc < 4; ++kc)
      qa[kc] = *reinterpret_cast<const bf16x8*>(qrow + 32 * kc);
  }
  f32x4 acc[8];
  #pragma unroll
  for (int i = 0; i < 8; ++i) acc[i] = (f32x4){0.f, 0.f, 0.f, 0.f};
  float m2[4], lsum[4];
  #pragma unroll
  for (int j = 0; j < 4; ++j) { m2[j] = -1e30f; lsum[j] = 0.f; }

  const u16* ktb = kt + ((size_t)(b * 4096 + sp * 1024)) * 128;
  const u16* vvb = vv + ((size_t)b * 128) * 4096 + sp * 1024;

  auto stage = [&](int bufi, int kti) {
    #pragma unroll
    for (int i = 0; i < 4; ++i) {
      int n = (tid >> 4) + i * 16;
      int ck = (tid & 15) ^ (n & 7);
      gll16(ktb + (size_t)(kti * 64 + n) * 128 + ck * 8, kS[bufi] + tid * 16 + i * 4096);
    }
    #pragma unroll
    for (int i = 0; i < 4; ++i) {
      int c = (tid >> 3) + i * 32;
      int ck = (tid & 7) ^ (c & 7);
      gll16(vvb + (size_t)c * 4096 + kti * 64 + ck * 8, vS[bufi] + tid * 16 + i * 4096);
    }
  };

  stage(0, 0);
  __syncthreads();
  int buf = 0;

  for (int kti = 0; kti < 16; ++kti) {
    if (kti < 15) stage(buf ^ 1, kti + 1);  // prefetch next tile; hidden under compute

    // S = Q K^T  (per wave: 16 q rows x 64 k cols); alpha pre-folded into Q
    f32x4 s[4];
    #pragma unroll
    for (int fn = 0; fn < 4; ++fn) s[fn] = (f32x4){0.f, 0.f, 0.f, 0.f};
    __builtin_amdgcn_s_setprio(1);
    #pragma unroll
    for (int kc = 0; kc < 4; ++kc) {
      int c2 = (lg * 8 + 32 * kc) * 2;
      bf16x8 a = qa[kc];
      #pragma unroll
      for (int fn = 0; fn < 4; ++fn) {
        int kp = lr + 16 * fn;
        bf16x8 bb = *reinterpret_cast<const bf16x8*>(kS[buf] + ((kp * 256 + c2) ^ ((kp & 7) << 4)));
        s[fn] = __builtin_amdgcn_mfma_f32_16x16x32_bf16(a, bb, s[fn], 0, 0, 0);
      }
    }
    __builtin_amdgcn_s_setprio(0);

    // online softmax, base-2, defer-max (THR=8), lane-local fast path
    float mt[4];
    #pragma unroll
    for (int j = 0; j < 4; ++j)
      mt[j] = fmaxf(fmaxf(s[0][j], s[1][j]), fmaxf(s[2][j], s[3][j]));
    bool grow = (mt[0] > m2[0] + 8.f) || (mt[1] > m2[1] + 8.f) ||
                (mt[2] > m2[2] + 8.f) || (mt[3] > m2[3] + 8.f);
    if (__any(grow)) {
      #pragma unroll
      for (int off = 1; off < 16; off <<= 1)
        #pragma unroll
        for (int j = 0; j < 4; ++j)
          mt[j] = fmaxf(mt[j], __shfl_xor(mt[j], off));
      float r[4];
      #pragma unroll
      for (int j = 0; j < 4; ++j) {
        float mn = fmaxf(m2[j], mt[j]);
        r[j] = exp2f(m2[j] - mn);
        m2[j] = mn;
        lsum[j] *= r[j];
      }
      #pragma unroll
      for (int fc = 0; fc < 8; ++fc)
        #pragma unroll
        for (int j = 0; j < 4; ++j) acc[fc][j] *= r[j];
    }
    // P = exp2(S - m2); per-lane partial lsum; P -> LDS bf16 (per-wave rows)
    #pragma unroll
    for (int fn = 0; fn < 4; ++fn)
      #pragma unroll
      for (int j = 0; j < 4; ++j) {
        float p = exp2f(s[fn][j] - m2[j]);
        lsum[j] += p;
        int qg = 16 * w + lg * 4 + j;
        int kp = lr + 16 * fn;
        *reinterpret_cast<bf16_t*>(pS + ((qg * 128 + kp * 2) ^ ((qg & 7) << 4))) = (bf16_t)p;
      }
    // PV: acc[q, c] += P[q, k] * V[c, k]
    __builtin_amdgcn_s_setprio(1);
    #pragma unroll
    for (int kc = 0; kc < 2; ++kc) {
      int qg = 16 * w + lr;
      int k2 = (lg * 8 + 32 * kc) * 2;
      bf16x8 pa = *reinterpret_cast<const bf16x8*>(pS + ((qg * 128 + k2) ^ ((qg & 7) << 4)));
      #pragma unroll
      for (int fc = 0; fc < 8; ++fc) {
        int c = lr + 16 * fc;
        bf16x8 vb = *reinterpret_cast<const bf16x8*>(vS[buf] + ((c * 128 + k2) ^ ((c & 7) << 4)));
        acc[fc] = __builtin_amdgcn_mfma_f32_16x16x32_bf16(pa, vb, acc[fc], 0, 0, 0);
      }
    }
    __builtin_amdgcn_s_setprio(0);
    __syncthreads();  // drains prefetch vmcnt + releases buf for next-tile staging
    buf ^= 1;
  }
  // cross-lane lsum reduce (deferred to once per kernel)
  #pragma unroll
  for (int off = 1; off < 16; off <<= 1)
    #pragma unroll
    for (int j = 0; j < 4; ++j)
      lsum[j] += __shfl_xor(lsum[j], off);
  // write unnormalized partial O (bf16) + per-row (m, l)
  #pragma unroll
  for (int j = 0; j < 4; ++j) {
    int nloc = 16 * w + lg * 4 + j;
    size_t row = (size_t)(sp * 16384 + b * 4096 + q0 + nloc);
    bf16_t* orow = (bf16_t*)(opart + row * 128 + lr);
    #pragma unroll
    for (int fc = 0; fc < 8; ++fc)
      orow[16 * fc] = (bf16_t)(acc[fc][j]);
    if (lr == 0) {
      ml[row * 2] = m2[j];
      ml[row * 2 + 1] = lsum[j];
    }
  }
}

// ------- Proj GEMM + fused split-merge + bias + residual: out = x + Wp @ merge(opart) -------
__global__ __launch_bounds__(256) void proj_kernel(const float* __restrict__ wp,
                                                   const float* __restrict__ bp,
                                                   const u16* __restrict__ opart,
                                                   const float* __restrict__ ml,
                                                   const float* __restrict__ x,
                                                   float* __restrict__ out) {
  __shared__ char aS[16384];
  __shared__ char bS[16384];
  int b = blockIdx.z;
  int o0 = blockIdx.y * 64;
  int n0 = blockIdx.x * 64;
  int tid = threadIdx.x;
  #pragma unroll
  for (int i = 0; i < 8; ++i) {
    int chunk = tid + (i << 8);
    int o = chunk >> 5, cj = (chunk & 31) << 2;
    float4 f = *reinterpret_cast<const float4*>(wp + (o0 + o) * 128 + cj);
    u16 h0 = __builtin_bit_cast(u16, (bf16_t)f.x);
    u16 h1 = __builtin_bit_cast(u16, (bf16_t)f.y);
    u16 h2 = __builtin_bit_cast(u16, (bf16_t)f.z);
    u16 h3 = __builtin_bit_cast(u16, (bf16_t)f.w);
    *reinterpret_cast<ushort4*>(aS + ((o * 256 + cj * 2) ^ ((o & 7) << 4))) = make_ushort4(h0, h1, h2, h3);
  }
  // B-stage: merge 4 kv-splits inline -> bf16 h[n][c]
  #pragma unroll
  for (int i = 0; i < 4; ++i) {
    int chunk = tid + (i << 8);
    int n = chunk >> 4, ch = chunk & 15;
    size_t bn = (size_t)(b * 4096 + n0 + n);
    float m[4], lv[4];
    #pragma unroll
    for (int s = 0; s < 4; ++s) {
      m[s] = ml[((size_t)(s * 16384) + bn) * 2];
      lv[s] = ml[((size_t)(s * 16384) + bn) * 2 + 1];
    }
    float M = fmaxf(fmaxf(m[0], m[1]), fmaxf(m[2], m[3]));
    float wgt[4], L = 0.f;
    #pragma unroll
    for (int s = 0; s < 4; ++s) {
      wgt[s] = exp2f(m[s] - M);
      L += wgt[s] * lv[s];
    }
    float inv = 1.f / L;
    float o[8] = {0.f, 0.f, 0.f, 0.f, 0.f, 0.f, 0.f, 0.f};
    #pragma unroll
    for (int s = 0; s < 4; ++s) {
      uint4 pr = *reinterpret_cast<const uint4*>(opart + ((size_t)(s * 16384) + bn) * 128 + ch * 8);
      o[0] += wgt[s] * bfu2f(pr.x & 0xffffu);
      o[1] += wgt[s] * bfu2f(pr.x >> 16);
      o[2] += wgt[s] * bfu2f(pr.y & 0xffffu);
      o[3] += wgt[s] * bfu2f(pr.y >> 16);
      o[4] += wgt[s] * bfu2f(pr.z & 0xffffu);
      o[5] += wgt[s] * bfu2f(pr.z >> 16);
      o[6] += wgt[s] * bfu2f(pr.w & 0xffffu);
      o[7] += wgt[s] * bfu2f(pr.w >> 16);
    }
    u16 h[8];
    #pragma unroll
    for (int e = 0; e < 8; ++e) h[e] = __builtin_bit_cast(u16, (bf16_t)(o[e] * inv));
    uint4 packed;
    packed.x = (u32)h[0] | ((u32)h[1] << 16);
    packed.y = (u32)h[2] | ((u32)h[3] << 16);
    packed.z = (u32)h[4] | ((u32)h[5] << 16);
    packed.w = (u32)h[6] | ((u32)h[7] << 16);
    *reinterpret_cast<uint4*>(bS + ((n * 256 + ch * 16) ^ ((n & 7) << 4))) = packed;
  }
  __syncthreads();
  int w = tid >> 6, l = tid & 63, lr = l & 15, lg = l >> 4;
  f32x4 acc[4] = {{0,0,0,0},{0,0,0,0},{0,0,0,0},{0,0,0,0}};
  int orow = 16 * w + lr;
  #pragma unroll
  for (int kc = 0; kc < 4; ++kc) {
    int c2 = (lg * 8 + 32 * kc) * 2;
    bf16x8 a = *reinterpret_cast<const bf16x8*>(aS + ((orow * 256 + c2) ^ ((orow & 7) << 4)));
    #pragma unroll
    for (int fn = 0; fn < 4; ++fn) {
      int n = lr + 16 * fn;
      bf16x8 bb = *reinterpret_cast<const bf16x8*>(bS + ((n * 256 + c2) ^ ((n & 7) << 4)));
      acc[fn] = __builtin_amdgcn_mfma_f32_16x16x32_bf16(a, bb, acc[fn], 0, 0, 0);
    }
  }
  #pragma unroll
  for (int fn = 0; fn < 4; ++fn) {
    #pragma unroll
    for (int j = 0; j < 4; ++j) {
      int o = o0 + 16 * w + lg * 4 + j;
      int n = n0 + lr + 16 * fn;
      size_t idx = ((size_t)(b * 128 + o)) * 4096 + n;
      out[idx] = acc[fn][j] + bp[o] + x[idx];
    }
  }
}

extern "C" void kernel_launch(void* const* d_in, const int* in_sizes, int n_in,
                              void* d_out, int out_size, void* d_ws, size_t ws_size,
                              hipStream_t stream) {
  const float* x      = (const float*)d_in[0];
  const float* gamma  = (const float*)d_in[1];
  const float* beta   = (const float*)d_in[2];
  const float* w_qkv  = (const float*)d_in[3];
  const float* b_qkv  = (const float*)d_in[4];
  const float* w_proj = (const float*)d_in[5];
  const float* b_proj = (const float*)d_in[6];
  float* out = (float*)d_out;

  char* ws = (char*)d_ws;
  u16* xnt   = (u16*)(ws);               // 4 MB, [B,N,C] bf16
  u16* qt    = (u16*)(ws + (4u << 20));  // 4 MB, [B,N,C] (pre-scaled by alpha)
  u16* kt    = (u16*)(ws + (8u << 20));  // 4 MB, [B,N,C]
  u16* vv    = (u16*)(ws + (12u << 20)); // 4 MB, [B,C,N]
  u16* opart = (u16*)(ws + (16u << 20)); // 16 MB, [4 splits][B*N][C] bf16
  float* ml    = (float*)(ws + (48u << 20)); // 512 KB, [4 splits][B*N][2] f32
  float* parts = (float*)(ws + (49u << 20)); // 4 KB, GN partial sums [32][16][2]

  hipLaunchKernelGGL(gn_stats, dim3(512), dim3(256), 0, stream, x, parts);
  hipLaunchKernelGGL(gn_norm, dim3(512), dim3(256), 0, stream, x, gamma, beta, parts, xnt);
  hipLaunchKernelGGL(qkv_kernel, dim3(64, 6, 4), dim3(256), 0, stream, w_qkv, b_qkv, xnt, qt, kt, vv);
  hipLaunchKernelGGL(attn_kernel, dim3(64, 4, 4), dim3(256), 0, stream, qt, kt, vv, opart, ml);
  hipLaunchKernelGGL(proj_kernel, dim3(64, 2, 4), dim3(256), 0, stream, w_proj, b_proj, opart, ml, x, out);
}

// Round 10
// 142.402 us; speedup vs baseline: 1.9476x; 1.1941x over previous
//
#include <hip/hip_runtime.h>

typedef __bf16 bf16_t;
typedef bf16_t bf16x8 __attribute__((ext_vector_type(8)));
typedef float f32x4 __attribute__((ext_vector_type(4)));
typedef float f32x16 __attribute__((ext_vector_type(16)));
typedef unsigned short u16;
typedef unsigned int u32;

__device__ __forceinline__ float bfu2f(u32 h) {
  union { u32 u; float f; } v; v.u = h << 16;
  return v.f;
}
// global -> LDS direct 16B load; LDS dest must be wave-uniform base + lane*16
__device__ __forceinline__ void gll16(const void* g, void* l) {
  __builtin_amdgcn_global_load_lds((const __attribute__((address_space(1))) unsigned int*)g,
                                   (__attribute__((address_space(3))) unsigned int*)l, 16, 0, 0);
}
__device__ __forceinline__ u32 cvtpk(float lo, float hi) {
  u32 r;
  asm("v_cvt_pk_bf16_f32 %0, %1, %2" : "=v"(r) : "v"(lo), "v"(hi));
  return r;
}

// ---------------- GroupNorm stats: partial sums per (b,g,chunk) -----------------
__global__ __launch_bounds__(256) void gn_stats(const float* __restrict__ x,
                                                float* __restrict__ partial) {
  int bg = blockIdx.x >> 4, ck = blockIdx.x & 15;
  int tid = threadIdx.x;
  const float4* base = reinterpret_cast<const float4*>(x + (size_t)bg * 65536 + ck * 4096);
  float s = 0.f, sq = 0.f;
  #pragma unroll
  for (int j = 0; j < 4; ++j) {
    float4 v = base[j * 256 + tid];
    s += v.x + v.y + v.z + v.w;
    sq += v.x * v.x + v.y * v.y + v.z * v.z + v.w * v.w;
  }
  #pragma unroll
  for (int off = 32; off > 0; off >>= 1) {
    s += __shfl_down(s, off);
    sq += __shfl_down(sq, off);
  }
  __shared__ float red[8];
  int wid = tid >> 6;
  if ((tid & 63) == 0) { red[wid] = s; red[4 + wid] = sq; }
  __syncthreads();
  if (tid == 0) {
    float ts = red[0] + red[1] + red[2] + red[3];
    float tq = red[4] + red[5] + red[6] + red[7];
    partial[(bg * 16 + ck) * 2] = ts;
    partial[(bg * 16 + ck) * 2 + 1] = tq;
  }
}

// ------- GroupNorm normalize: x[B,C,N] -> xn_t[B,N,C] bf16, fully-coalesced writes -------
// grid 256 = 4 b x 64 n-chunks of 64; thread handles 8 consecutive channels
__global__ __launch_bounds__(256) void gn_norm(const float* __restrict__ x,
                                               const float* __restrict__ gamma,
                                               const float* __restrict__ beta,
                                               const float* __restrict__ partial,
                                               u16* __restrict__ xnt) {
  int b = blockIdx.x >> 6, nc = blockIdx.x & 63;
  int tid = threadIdx.x;
  int cbase = (tid & 15) * 8;
  int g = cbase >> 4;
  float s = 0.f, sq = 0.f;
  #pragma unroll
  for (int k = 0; k < 16; ++k) {
    s += partial[((b * 8 + g) * 16 + k) * 2];
    sq += partial[((b * 8 + g) * 16 + k) * 2 + 1];
  }
  float mean = s * (1.f / 65536.f);
  float var = sq * (1.f / 65536.f) - mean * mean;
  float rstd = rsqrtf(var + 1e-6f);
  float ga[8], be[8];
  #pragma unroll
  for (int j = 0; j < 8; ++j) {
    ga[j] = gamma[cbase + j] * rstd;
    be[j] = beta[cbase + j] - mean * ga[j];
  }
  int n0 = nc * 64;
  #pragma unroll
  for (int it = 0; it < 4; ++it) {
    int n = n0 + it * 16 + (tid >> 4);
    union { u16 s[8]; uint4 u; } pk;
    #pragma unroll
    for (int j = 0; j < 8; ++j) {
      float v = x[((size_t)(b * 128 + cbase + j)) * 4096 + n] * ga[j] + be[j];
      pk.s[j] = __builtin_bit_cast(u16, (bf16_t)v);
    }
    *reinterpret_cast<uint4*>(xnt + ((size_t)(b * 4096 + n)) * 128 + cbase) = pk.u;
  }
}

// ---------------- QKV GEMM: w_qkv[384,128] @ xn -> q_t,k_t [B,N,C], v [B,C,N] ----
// q pre-scaled by alpha; q/k epilogue transposed through LDS for coalesced writes
__global__ __launch_bounds__(256) void qkv_kernel(const float* __restrict__ wq,
                                                  const float* __restrict__ bq,
                                                  const u16* __restrict__ xnt,
                                                  u16* __restrict__ qt,
                                                  u16* __restrict__ kt,
                                                  u16* __restrict__ vv) {
  __shared__ char aS[16384];  // [o 0..63][c 0..127] bf16, swizzled; reused as transpose tile
  __shared__ char bS[16384];  // [n 0..63][c 0..127] bf16, swizzled
  int b = blockIdx.z;
  int o0 = blockIdx.y * 64;
  int n0 = blockIdx.x * 64;
  int tid = threadIdx.x;
  #pragma unroll
  for (int i = 0; i < 8; ++i) {
    int chunk = tid + (i << 8);
    int o = chunk >> 5, cj = (chunk & 31) << 2;
    float4 f = *reinterpret_cast<const float4*>(wq + (o0 + o) * 128 + cj);
    u16 h0 = __builtin_bit_cast(u16, (bf16_t)f.x);
    u16 h1 = __builtin_bit_cast(u16, (bf16_t)f.y);
    u16 h2 = __builtin_bit_cast(u16, (bf16_t)f.z);
    u16 h3 = __builtin_bit_cast(u16, (bf16_t)f.w);
    *reinterpret_cast<ushort4*>(aS + ((o * 256 + cj * 2) ^ ((o & 7) << 4))) = make_ushort4(h0, h1, h2, h3);
  }
  #pragma unroll
  for (int i = 0; i < 4; ++i) {
    int chunk = tid + (i << 8);
    int n = chunk >> 4, ch = chunk & 15;
    uint4 d = *reinterpret_cast<const uint4*>(xnt + ((size_t)(b * 4096 + n0 + n)) * 128 + ch * 8);
    *reinterpret_cast<uint4*>(bS + ((n * 256 + ch * 16) ^ ((n & 7) << 4))) = d;
  }
  __syncthreads();
  int w = tid >> 6, l = tid & 63, lr = l & 15, lg = l >> 4;
  f32x4 acc[4] = {{0,0,0,0},{0,0,0,0},{0,0,0,0},{0,0,0,0}};
  int orow = 16 * w + lr;
  #pragma unroll
  for (int kc = 0; kc < 4; ++kc) {
    int c2 = (lg * 8 + 32 * kc) * 2;
    bf16x8 a = *reinterpret_cast<const bf16x8*>(aS + ((orow * 256 + c2) ^ ((orow & 7) << 4)));
    #pragma unroll
    for (int fn = 0; fn < 4; ++fn) {
      int n = lr + 16 * fn;
      bf16x8 bb = *reinterpret_cast<const bf16x8*>(bS + ((n * 256 + c2) ^ ((n & 7) << 4)));
      acc[fn] = __builtin_amdgcn_mfma_f32_16x16x32_bf16(a, bb, acc[fn], 0, 0, 0);
    }
  }
  const float alpha = 0.12753325f;  // 128^-0.5 * log2(e)
  if (o0 < 256) {
    // q or k output: transpose 64(o) x 64(n) tile through LDS, then coalesced 16B stores
    bool isq = (o0 < 128);
    __syncthreads();
    u16* tS = (u16*)aS;  // stride 68 u16 to break bank alignment
    #pragma unroll
    for (int fn = 0; fn < 4; ++fn) {
      #pragma unroll
      for (int j = 0; j < 4; ++j) {
        int o_loc = 16 * w + lg * 4 + j;
        int n_loc = lr + 16 * fn;
        float v = acc[fn][j] + bq[o0 + o_loc];
        if (isq) v *= alpha;
        tS[o_loc * 68 + n_loc] = __builtin_bit_cast(u16, (bf16_t)v);
      }
    }
    __syncthreads();
    u16* dst = isq ? qt : kt;
    int obase = o0 & 127;
    #pragma unroll
    for (int it = 0; it < 2; ++it) {
      int n_l = (tid >> 3) + it * 32;
      int oc = (tid & 7) * 8;
      union { u16 s[8]; uint4 u; } pk;
      #pragma unroll
      for (int k2 = 0; k2 < 8; ++k2) pk.s[k2] = tS[(oc + k2) * 68 + n_l];
      *reinterpret_cast<uint4*>(dst + ((size_t)(b * 4096 + n0 + n_l)) * 128 + obase + oc) = pk.u;
    }
  } else {
    #pragma unroll
    for (int fn = 0; fn < 4; ++fn) {
      #pragma unroll
      for (int j = 0; j < 4; ++j) {
        int o_loc = 16 * w + lg * 4 + j;
        int n = n0 + lr + 16 * fn;
        float v = acc[fn][j] + bq[o0 + o_loc];
        ((bf16_t*)vv)[((size_t)(b * 128 + (o0 - 256) + o_loc)) * 4096 + n] = (bf16_t)v;
      }
    }
  }
}

// ---- Flash attention v2: 32x32 MFMA, swapped QK^T, in-register P (T12), split-KV ----
// grid (32 q-tiles of 128, 4 kv-splits, 4 b); 4 waves, wave w owns q-rows w*32..w*32+31
__global__ __launch_bounds__(256, 2) void attn_kernel(const u16* __restrict__ qt,
                                                      const u16* __restrict__ kt,
                                                      const u16* __restrict__ vv,
                                                      u16* __restrict__ opart,
                                                      float* __restrict__ ml) {
  __shared__ char kS[2][16384];  // [k 0..63][c 0..127] bf16, swizzled ^((k&7)<<4)
  __shared__ char vS[2][16384];  // [c 0..127][k 0..63] bf16, swizzled ^((c&7)<<4)
  int b = blockIdx.z;
  int sp = blockIdx.y;
  int q0 = blockIdx.x * 128;
  int tid = threadIdx.x;
  int w = tid >> 6, l = tid & 63, lq = l & 31, h = l >> 5;

  // Q preload: lane owns q-row q0 + w*32 + lq; c-slices (cs*16 + h*8 .. +7)
  bf16x8 qf[8];
  {
    const u16* qrow = qt + ((size_t)(b * 4096 + q0 + w * 32 + lq)) * 128 + h * 8;
    #pragma unroll
    for (int cs = 0; cs < 8; ++cs)
      qf[cs] = *reinterpret_cast<const bf16x8*>(qrow + cs * 16);
  }
  f32x16 acc[4];
  #pragma unroll
  for (int cc = 0; cc < 4; ++cc)
    #pragma unroll
    for (int i = 0; i < 16; ++i) acc[cc][i] = 0.f;
  float m2 = -1e30f, lsum = 0.f;

  const u16* ktb = kt + ((size_t)(b * 4096 + sp * 1024)) * 128;
  const u16* vvb = vv + ((size_t)b * 128) * 4096 + sp * 1024;

  auto stage = [&](int bufi, int kti) {
    #pragma unroll
    for (int i = 0; i < 4; ++i) {
      int n = (tid >> 4) + i * 16;
      int ck = (tid & 15) ^ (n & 7);
      gll16(ktb + (size_t)(kti * 64 + n) * 128 + ck * 8, kS[bufi] + tid * 16 + i * 4096);
    }
    #pragma unroll
    for (int i = 0; i < 4; ++i) {
      int c = (tid >> 3) + i * 32;
      int ck = (tid & 7) ^ (c & 7);
      gll16(vvb + (size_t)c * 4096 + kti * 64 + ck * 8, vS[bufi] + tid * 16 + i * 4096);
    }
  };

  stage(0, 0);
  __syncthreads();
  int buf = 0;

  for (int kti = 0; kti < 16; ++kti) {
    if (kti < 15) stage(buf ^ 1, kti + 1);  // prefetch next tile under compute

    // S^T = K . Q^T : st[ks][reg] = S[k = ks*32 + (reg&3)+8*(reg>>2)+4h][q = lq]
    f32x16 st0, st1;
    #pragma unroll
    for (int i = 0; i < 16; ++i) { st0[i] = 0.f; st1[i] = 0.f; }
    __builtin_amdgcn_s_setprio(1);
    #pragma unroll
    for (int cs = 0; cs < 8; ++cs) {
      int co = cs * 32 + h * 16;  // byte offset of c-slice within 256B row
      bf16x8 kf0 = *reinterpret_cast<const bf16x8*>(kS[buf] + ((lq * 256 + co) ^ ((lq & 7) << 4)));
      st0 = __builtin_amdgcn_mfma_f32_32x32x16_bf16(kf0, qf[cs], st0, 0, 0, 0);
      int kr1 = 32 + lq;
      bf16x8 kf1 = *reinterpret_cast<const bf16x8*>(kS[buf] + ((kr1 * 256 + co) ^ ((kr1 & 7) << 4)));
      st1 = __builtin_amdgcn_mfma_f32_32x32x16_bf16(kf1, qf[cs], st1, 0, 0, 0);
    }
    __builtin_amdgcn_s_setprio(0);

    // online softmax: lane owns full q-row slice (32 of 64 k); pair lane l^32 has the rest
    float mt = st0[0];
    #pragma unroll
    for (int i = 1; i < 16; ++i) mt = fmaxf(mt, st0[i]);
    #pragma unroll
    for (int i = 0; i < 16; ++i) mt = fmaxf(mt, st1[i]);
    mt = fmaxf(mt, __shfl_xor(mt, 32));
    if (__any(mt > m2 + 8.f)) {  // defer-max THR=8 (base-2)
      float mn = fmaxf(m2, mt);
      float r = exp2f(m2 - mn);
      m2 = mn;
      lsum *= r;
      #pragma unroll
      for (int reg = 0; reg < 16; ++reg) {
        int qrow = (reg & 3) + 8 * (reg >> 2) + 4 * h;
        float rq = __shfl(r, qrow);
        #pragma unroll
        for (int cc = 0; cc < 4; ++cc) acc[cc][reg] *= rq;
      }
    }
    // P = exp2(S - m2) in-register; redistribute across lane-halves into PV A-frags
    bf16x8 pa[4];
    #pragma unroll
    for (int ks = 0; ks < 2; ++ks) {
      float p[16];
      #pragma unroll
      for (int i = 0; i < 16; ++i) {
        float sv = (ks == 0) ? st0[i] : st1[i];
        p[i] = exp2f(sv - m2);
        lsum += p[i];
      }
      #pragma unroll
      for (int kk = 0; kk < 2; ++kk) {
        int r0 = kk * 8, r1 = kk * 8 + 4;
        u32 a1 = cvtpk(p[r0 + 0], p[r0 + 1]);
        u32 a2 = cvtpk(p[r0 + 2], p[r0 + 3]);
        u32 b1 = cvtpk(p[r1 + 0], p[r1 + 1]);
        u32 b2 = cvtpk(p[r1 + 2], p[r1 + 3]);
        u32 sa1 = (u32)__shfl_xor((int)a1, 32);
        u32 sa2 = (u32)__shfl_xor((int)a2, 32);
        u32 sb1 = (u32)__shfl_xor((int)b1, 32);
        u32 sb2 = (u32)__shfl_xor((int)b2, 32);
        union { u32 wd[4]; bf16x8 v; } af;
        af.wd[0] = h ? sb1 : a1;
        af.wd[1] = h ? sb2 : a2;
        af.wd[2] = h ? b1 : sa1;
        af.wd[3] = h ? b2 : sa2;
        pa[ks * 2 + kk] = af.v;
      }
    }
    // PV: acc[cc] += P[q][k-slice ks2] * V[k][c = cc*32 + lq]
    __builtin_amdgcn_s_setprio(1);
    #pragma unroll
    for (int ks2 = 0; ks2 < 4; ++ks2) {
      int ko = ks2 * 32 + h * 16;  // byte offset of k-slice within 128B row
      #pragma unroll
      for (int cc = 0; cc < 4; ++cc) {
        int c = cc * 32 + lq;
        bf16x8 vf = *reinterpret_cast<const bf16x8*>(vS[buf] + ((c * 128 + ko) ^ ((c & 7) << 4)));
        acc[cc] = __builtin_amdgcn_mfma_f32_32x32x16_bf16(pa[ks2], vf, acc[cc], 0, 0, 0);
      }
    }
    __builtin_amdgcn_s_setprio(0);
    __syncthreads();  // drains prefetch + releases buf
    buf ^= 1;
  }
  // merge pair-lane partial sums (q-row split across l and l^32)
  lsum += __shfl_xor(lsum, 32);
  // write unnormalized partial O (bf16) + per-row (m, l)
  #pragma unroll
  for (int reg = 0; reg < 16; ++reg) {
    int qrow = (reg & 3) + 8 * (reg >> 2) + 4 * h;
    size_t row = (size_t)(sp * 16384 + b * 4096 + q0 + w * 32 + qrow);
    bf16_t* orow = (bf16_t*)opart + row * 128 + lq;
    #pragma unroll
    for (int cc = 0; cc < 4; ++cc)
      orow[cc * 32] = (bf16_t)acc[cc][reg];
  }
  if (l < 32) {
    size_t row = (size_t)(sp * 16384 + b * 4096 + q0 + w * 32 + l);
    ml[row * 2] = m2;
    ml[row * 2 + 1] = lsum;
  }
}

// ------- Proj GEMM + fused split-merge + bias + residual: out = x + Wp @ merge(opart) -------
__global__ __launch_bounds__(256) void proj_kernel(const float* __restrict__ wp,
                                                   const float* __restrict__ bp,
                                                   const u16* __restrict__ opart,
                                                   const float* __restrict__ ml,
                                                   const float* __restrict__ x,
                                                   float* __restrict__ out) {
  __shared__ char aS[16384];
  __shared__ char bS[16384];
  int b = blockIdx.z;
  int o0 = blockIdx.y * 64;
  int n0 = blockIdx.x * 64;
  int tid = threadIdx.x;
  #pragma unroll
  for (int i = 0; i < 8; ++i) {
    int chunk = tid + (i << 8);
    int o = chunk >> 5, cj = (chunk & 31) << 2;
    float4 f = *reinterpret_cast<const float4*>(wp + (o0 + o) * 128 + cj);
    u16 h0 = __builtin_bit_cast(u16, (bf16_t)f.x);
    u16 h1 = __builtin_bit_cast(u16, (bf16_t)f.y);
    u16 h2 = __builtin_bit_cast(u16, (bf16_t)f.z);
    u16 h3 = __builtin_bit_cast(u16, (bf16_t)f.w);
    *reinterpret_cast<ushort4*>(aS + ((o * 256 + cj * 2) ^ ((o & 7) << 4))) = make_ushort4(h0, h1, h2, h3);
  }
  // B-stage: merge 4 kv-splits inline -> bf16 h[n][c]
  #pragma unroll
  for (int i = 0; i < 4; ++i) {
    int chunk = tid + (i << 8);
    int n = chunk >> 4, ch = chunk & 15;
    size_t bn = (size_t)(b * 4096 + n0 + n);
    float m[4], lv[4];
    #pragma unroll
    for (int s = 0; s < 4; ++s) {
      m[s] = ml[((size_t)(s * 16384) + bn) * 2];
      lv[s] = ml[((size_t)(s * 16384) + bn) * 2 + 1];
    }
    float M = fmaxf(fmaxf(m[0], m[1]), fmaxf(m[2], m[3]));
    float wgt[4], L = 0.f;
    #pragma unroll
    for (int s = 0; s < 4; ++s) {
      wgt[s] = exp2f(m[s] - M);
      L += wgt[s] * lv[s];
    }
    float inv = 1.f / L;
    float o[8] = {0.f, 0.f, 0.f, 0.f, 0.f, 0.f, 0.f, 0.f};
    #pragma unroll
    for (int s = 0; s < 4; ++s) {
      uint4 pr = *reinterpret_cast<const uint4*>(opart + ((size_t)(s * 16384) + bn) * 128 + ch * 8);
      o[0] += wgt[s] * bfu2f(pr.x & 0xffffu);
      o[1] += wgt[s] * bfu2f(pr.x >> 16);
      o[2] += wgt[s] * bfu2f(pr.y & 0xffffu);
      o[3] += wgt[s] * bfu2f(pr.y >> 16);
      o[4] += wgt[s] * bfu2f(pr.z & 0xffffu);
      o[5] += wgt[s] * bfu2f(pr.z >> 16);
      o[6] += wgt[s] * bfu2f(pr.w & 0xffffu);
      o[7] += wgt[s] * bfu2f(pr.w >> 16);
    }
    u16 hh[8];
    #pragma unroll
    for (int e = 0; e < 8; ++e) hh[e] = __builtin_bit_cast(u16, (bf16_t)(o[e] * inv));
    uint4 packed;
    packed.x = (u32)hh[0] | ((u32)hh[1] << 16);
    packed.y = (u32)hh[2] | ((u32)hh[3] << 16);
    packed.z = (u32)hh[4] | ((u32)hh[5] << 16);
    packed.w = (u32)hh[6] | ((u32)hh[7] << 16);
    *reinterpret_cast<uint4*>(bS + ((n * 256 + ch * 16) ^ ((n & 7) << 4))) = packed;
  }
  __syncthreads();
  int w = tid >> 6, l = tid & 63, lr = l & 15, lg = l >> 4;
  f32x4 acc[4] = {{0,0,0,0},{0,0,0,0},{0,0,0,0},{0,0,0,0}};
  int orow = 16 * w + lr;
  #pragma unroll
  for (int kc = 0; kc < 4; ++kc) {
    int c2 = (lg * 8 + 32 * kc) * 2;
    bf16x8 a = *reinterpret_cast<const bf16x8*>(aS + ((orow * 256 + c2) ^ ((orow & 7) << 4)));
    #pragma unroll
    for (int fn = 0; fn < 4; ++fn) {
      int n = lr + 16 * fn;
      bf16x8 bb = *reinterpret_cast<const bf16x8*>(bS + ((n * 256 + c2) ^ ((n & 7) << 4)));
      acc[fn] = __builtin_amdgcn_mfma_f32_16x16x32_bf16(a, bb, acc[fn], 0, 0, 0);
    }
  }
  #pragma unroll
  for (int fn = 0; fn < 4; ++fn) {
    #pragma unroll
    for (int j = 0; j < 4; ++j) {
      int o = o0 + 16 * w + lg * 4 + j;
      int n = n0 + lr + 16 * fn;
      size_t idx = ((size_t)(b * 128 + o)) * 4096 + n;
      out[idx] = acc[fn][j] + bp[o] + x[idx];
    }
  }
}

extern "C" void kernel_launch(void* const* d_in, const int* in_sizes, int n_in,
                              void* d_out, int out_size, void* d_ws, size_t ws_size,
                              hipStream_t stream) {
  const float* x      = (const float*)d_in[0];
  const float* gamma  = (const float*)d_in[1];
  const float* beta   = (const float*)d_in[2];
  const float* w_qkv  = (const float*)d_in[3];
  const float* b_qkv  = (const float*)d_in[4];
  const float* w_proj = (const float*)d_in[5];
  const float* b_proj = (const float*)d_in[6];
  float* out = (float*)d_out;

  char* ws = (char*)d_ws;
  u16* xnt   = (u16*)(ws);               // 4 MB, [B,N,C] bf16
  u16* qt    = (u16*)(ws + (4u << 20));  // 4 MB, [B,N,C] (pre-scaled by alpha)
  u16* kt    = (u16*)(ws + (8u << 20));  // 4 MB, [B,N,C]
  u16* vv    = (u16*)(ws + (12u << 20)); // 4 MB, [B,C,N]
  u16* opart = (u16*)(ws + (16u << 20)); // 16 MB, [4 splits][B*N][C] bf16
  float* ml    = (float*)(ws + (48u << 20)); // 512 KB, [4 splits][B*N][2] f32
  float* parts = (float*)(ws + (49u << 20)); // 4 KB, GN partial sums [32][16][2]

  hipLaunchKernelGGL(gn_stats, dim3(512), dim3(256), 0, stream, x, parts);
  hipLaunchKernelGGL(gn_norm, dim3(256), dim3(256), 0, stream, x, gamma, beta, parts, xnt);
  hipLaunchKernelGGL(qkv_kernel, dim3(64, 6, 4), dim3(256), 0, stream, w_qkv, b_qkv, xnt, qt, kt, vv);
  hipLaunchKernelGGL(attn_kernel, dim3(32, 4, 4), dim3(256), 0, stream, qt, kt, vv, opart, ml);
  hipLaunchKernelGGL(proj_kernel, dim3(64, 2, 4), dim3(256), 0, stream, w_proj, b_proj, opart, ml, x, out);
}

// Round 11
// 142.220 us; speedup vs baseline: 1.9501x; 1.0013x over previous
//
#include <hip/hip_runtime.h>

typedef __bf16 bf16_t;
typedef bf16_t bf16x8 __attribute__((ext_vector_type(8)));
typedef float f32x4 __attribute__((ext_vector_type(4)));
typedef float f32x16 __attribute__((ext_vector_type(16)));
typedef unsigned short u16;
typedef unsigned int u32;

__device__ __forceinline__ float bfu2f(u32 h) {
  union { u32 u; float f; } v; v.u = h << 16;
  return v.f;
}
// global -> LDS direct 16B load; LDS dest must be wave-uniform base + lane*16
__device__ __forceinline__ void gll16(const void* g, void* l) {
  __builtin_amdgcn_global_load_lds((const __attribute__((address_space(1))) unsigned int*)g,
                                   (__attribute__((address_space(3))) unsigned int*)l, 16, 0, 0);
}
__device__ __forceinline__ u32 cvtpk(float lo, float hi) {
  u32 r;
  asm("v_cvt_pk_bf16_f32 %0, %1, %2" : "=v"(r) : "v"(lo), "v"(hi));
  return r;
}

// ---------------- GroupNorm stats: partial sums per (b,g,chunk) -----------------
__global__ __launch_bounds__(256) void gn_stats(const float* __restrict__ x,
                                                float* __restrict__ partial) {
  int bg = blockIdx.x >> 4, ck = blockIdx.x & 15;
  int tid = threadIdx.x;
  const float4* base = reinterpret_cast<const float4*>(x + (size_t)bg * 65536 + ck * 4096);
  float s = 0.f, sq = 0.f;
  #pragma unroll
  for (int j = 0; j < 4; ++j) {
    float4 v = base[j * 256 + tid];
    s += v.x + v.y + v.z + v.w;
    sq += v.x * v.x + v.y * v.y + v.z * v.z + v.w * v.w;
  }
  #pragma unroll
  for (int off = 32; off > 0; off >>= 1) {
    s += __shfl_down(s, off);
    sq += __shfl_down(sq, off);
  }
  __shared__ float red[8];
  int wid = tid >> 6;
  if ((tid & 63) == 0) { red[wid] = s; red[4 + wid] = sq; }
  __syncthreads();
  if (tid == 0) {
    float ts = red[0] + red[1] + red[2] + red[3];
    float tq = red[4] + red[5] + red[6] + red[7];
    partial[(bg * 16 + ck) * 2] = ts;
    partial[(bg * 16 + ck) * 2 + 1] = tq;
  }
}

// ------- GroupNorm normalize: coalesced read -> LDS transpose -> coalesced write -------
// grid 256 = 4 b x 64 n-chunks of 64
__global__ __launch_bounds__(256) void gn_norm(const float* __restrict__ x,
                                               const float* __restrict__ gamma,
                                               const float* __restrict__ beta,
                                               const float* __restrict__ partial,
                                               u16* __restrict__ xnt) {
  __shared__ alignas(16) u16 tS[64 * 136];
  int b = blockIdx.x >> 6, nc = blockIdx.x & 63;
  int n0 = nc * 64;
  int tid = threadIdx.x;
  // phase 1: thread owns channel c = tid>>1, n-half nh; reads 128B contiguous
  int c = tid >> 1;
  int nh = (tid & 1) * 32;
  int g = c >> 4;
  float s = 0.f, sq = 0.f;
  #pragma unroll
  for (int k = 0; k < 16; ++k) {
    s += partial[((b * 8 + g) * 16 + k) * 2];
    sq += partial[((b * 8 + g) * 16 + k) * 2 + 1];
  }
  float mean = s * (1.f / 65536.f);
  float var = sq * (1.f / 65536.f) - mean * mean;
  float rstd = rsqrtf(var + 1e-6f);
  float ga = gamma[c] * rstd;
  float be = beta[c] - mean * ga;
  const float4* xr4 = reinterpret_cast<const float4*>(x + ((size_t)(b * 128 + c)) * 4096 + n0 + nh);
  #pragma unroll
  for (int i = 0; i < 8; ++i) {
    float4 v = xr4[i];
    int nb = nh + i * 4;
    tS[(nb + 0) * 136 + c] = __builtin_bit_cast(u16, (bf16_t)(v.x * ga + be));
    tS[(nb + 1) * 136 + c] = __builtin_bit_cast(u16, (bf16_t)(v.y * ga + be));
    tS[(nb + 2) * 136 + c] = __builtin_bit_cast(u16, (bf16_t)(v.z * ga + be));
    tS[(nb + 3) * 136 + c] = __builtin_bit_cast(u16, (bf16_t)(v.w * ga + be));
  }
  __syncthreads();
  // phase 2: thread owns (n, c-quad); 64B vectorized LDS read -> coalesced global write
  int n = tid >> 2, cq = (tid & 3) * 32;
  const uint4* src = reinterpret_cast<const uint4*>(tS + n * 136 + cq);
  uint4 a0 = src[0], a1 = src[1], a2 = src[2], a3 = src[3];
  uint4* dst = reinterpret_cast<uint4*>(xnt + ((size_t)(b * 4096 + n0 + n)) * 128 + cq);
  dst[0] = a0; dst[1] = a1; dst[2] = a2; dst[3] = a3;
}

// ------- QKV GEMM: block stages one xn tile, loops 3 o-tiles (grid y=2 halves) -------
// q pre-scaled by alpha; q/k epilogue transposed through LDS for coalesced writes
__global__ __launch_bounds__(256) void qkv_kernel(const float* __restrict__ wq,
                                                  const float* __restrict__ bq,
                                                  const u16* __restrict__ xnt,
                                                  u16* __restrict__ qt,
                                                  u16* __restrict__ kt,
                                                  u16* __restrict__ vv) {
  __shared__ char aS[16384];  // [o 0..63][c 0..127] bf16, swizzled
  __shared__ char bS[16384];  // [n 0..63][c 0..127] bf16, swizzled
  __shared__ alignas(16) u16 tS[64 * 68];  // transpose tile for q/k epilogue
  int b = blockIdx.z;
  int n0 = blockIdx.x * 64;
  int tid = threadIdx.x;
  // stage B (xn tile) once
  #pragma unroll
  for (int i = 0; i < 4; ++i) {
    int chunk = tid + (i << 8);
    int n = chunk >> 4, ch = chunk & 15;
    uint4 d = *reinterpret_cast<const uint4*>(xnt + ((size_t)(b * 4096 + n0 + n)) * 128 + ch * 8);
    *reinterpret_cast<uint4*>(bS + ((n * 256 + ch * 16) ^ ((n & 7) << 4))) = d;
  }
  int w = tid >> 6, l = tid & 63, lr = l & 15, lg = l >> 4;
  const float alpha = 0.12753325f;  // 128^-0.5 * log2(e)
  for (int oi = 0; oi < 3; ++oi) {
    int o0 = (blockIdx.y * 3 + oi) * 64;
    // stage A (weights) for this o-tile
    #pragma unroll
    for (int i = 0; i < 8; ++i) {
      int chunk = tid + (i << 8);
      int o = chunk >> 5, cj = (chunk & 31) << 2;
      float4 f = *reinterpret_cast<const float4*>(wq + (o0 + o) * 128 + cj);
      u16 h0 = __builtin_bit_cast(u16, (bf16_t)f.x);
      u16 h1 = __builtin_bit_cast(u16, (bf16_t)f.y);
      u16 h2 = __builtin_bit_cast(u16, (bf16_t)f.z);
      u16 h3 = __builtin_bit_cast(u16, (bf16_t)f.w);
      *reinterpret_cast<ushort4*>(aS + ((o * 256 + cj * 2) ^ ((o & 7) << 4))) = make_ushort4(h0, h1, h2, h3);
    }
    __syncthreads();
    f32x4 acc[4] = {{0,0,0,0},{0,0,0,0},{0,0,0,0},{0,0,0,0}};
    int orow = 16 * w + lr;
    #pragma unroll
    for (int kc = 0; kc < 4; ++kc) {
      int c2 = (lg * 8 + 32 * kc) * 2;
      bf16x8 a = *reinterpret_cast<const bf16x8*>(aS + ((orow * 256 + c2) ^ ((orow & 7) << 4)));
      #pragma unroll
      for (int fn = 0; fn < 4; ++fn) {
        int n = lr + 16 * fn;
        bf16x8 bb = *reinterpret_cast<const bf16x8*>(bS + ((n * 256 + c2) ^ ((n & 7) << 4)));
        acc[fn] = __builtin_amdgcn_mfma_f32_16x16x32_bf16(a, bb, acc[fn], 0, 0, 0);
      }
    }
    if (o0 < 256) {
      // q or k: transpose 64(o) x 64(n) through tS, then coalesced 16B stores
      bool isq = (o0 < 128);
      #pragma unroll
      for (int fn = 0; fn < 4; ++fn) {
        #pragma unroll
        for (int j = 0; j < 4; ++j) {
          int o_loc = 16 * w + lg * 4 + j;
          int n_loc = lr + 16 * fn;
          float v = acc[fn][j] + bq[o0 + o_loc];
          if (isq) v *= alpha;
          tS[o_loc * 68 + n_loc] = __builtin_bit_cast(u16, (bf16_t)v);
        }
      }
      __syncthreads();
      u16* dst = isq ? qt : kt;
      int obase = o0 & 127;
      #pragma unroll
      for (int it = 0; it < 2; ++it) {
        int n_l = (tid >> 3) + it * 32;
        int oc = (tid & 7) * 8;
        union { u16 s[8]; uint4 u; } pk;
        #pragma unroll
        for (int k2 = 0; k2 < 8; ++k2) pk.s[k2] = tS[(oc + k2) * 68 + n_l];
        *reinterpret_cast<uint4*>(dst + ((size_t)(b * 4096 + n0 + n_l)) * 128 + obase + oc) = pk.u;
      }
    } else {
      #pragma unroll
      for (int fn = 0; fn < 4; ++fn) {
        #pragma unroll
        for (int j = 0; j < 4; ++j) {
          int o_loc = 16 * w + lg * 4 + j;
          int n = n0 + lr + 16 * fn;
          float v = acc[fn][j] + bq[o0 + o_loc];
          ((bf16_t*)vv)[((size_t)(b * 128 + (o0 - 256) + o_loc)) * 4096 + n] = (bf16_t)v;
        }
      }
    }
    __syncthreads();  // aS/tS reads done before next-iter staging
  }
}

// ---- Flash attention v2: 32x32 MFMA, swapped QK^T, in-register P (T12), split-KV ----
// grid (32 q-tiles of 128, 4 kv-splits, 4 b); 4 waves, wave w owns q-rows w*32..w*32+31
__global__ __launch_bounds__(256, 2) void attn_kernel(const u16* __restrict__ qt,
                                                      const u16* __restrict__ kt,
                                                      const u16* __restrict__ vv,
                                                      u16* __restrict__ opart,
                                                      float* __restrict__ ml) {
  __shared__ char kS[2][16384];  // [k 0..63][c 0..127] bf16, swizzled ^((k&7)<<4)
  __shared__ char vS[2][16384];  // [c 0..127][k 0..63] bf16, swizzled ^((c&7)<<4)
  int b = blockIdx.z;
  int sp = blockIdx.y;
  int q0 = blockIdx.x * 128;
  int tid = threadIdx.x;
  int w = tid >> 6, l = tid & 63, lq = l & 31, h = l >> 5;

  // Q preload: lane owns q-row q0 + w*32 + lq; c-slices (cs*16 + h*8 .. +7)
  bf16x8 qf[8];
  {
    const u16* qrow = qt + ((size_t)(b * 4096 + q0 + w * 32 + lq)) * 128 + h * 8;
    #pragma unroll
    for (int cs = 0; cs < 8; ++cs)
      qf[cs] = *reinterpret_cast<const bf16x8*>(qrow + cs * 16);
  }
  f32x16 acc[4];
  #pragma unroll
  for (int cc = 0; cc < 4; ++cc)
    #pragma unroll
    for (int i = 0; i < 16; ++i) acc[cc][i] = 0.f;
  float m2 = -1e30f, lsum = 0.f;

  const u16* ktb = kt + ((size_t)(b * 4096 + sp * 1024)) * 128;
  const u16* vvb = vv + ((size_t)b * 128) * 4096 + sp * 1024;

  auto stage = [&](int bufi, int kti) {
    #pragma unroll
    for (int i = 0; i < 4; ++i) {
      int n = (tid >> 4) + i * 16;
      int ck = (tid & 15) ^ (n & 7);
      gll16(ktb + (size_t)(kti * 64 + n) * 128 + ck * 8, kS[bufi] + tid * 16 + i * 4096);
    }
    #pragma unroll
    for (int i = 0; i < 4; ++i) {
      int c = (tid >> 3) + i * 32;
      int ck = (tid & 7) ^ (c & 7);
      gll16(vvb + (size_t)c * 4096 + kti * 64 + ck * 8, vS[bufi] + tid * 16 + i * 4096);
    }
  };

  stage(0, 0);
  __syncthreads();
  int buf = 0;

  for (int kti = 0; kti < 16; ++kti) {
    if (kti < 15) stage(buf ^ 1, kti + 1);  // prefetch next tile under compute

    // S^T = K . Q^T : st[ks][reg] = S[k = ks*32 + (reg&3)+8*(reg>>2)+4h][q = lq]
    f32x16 st0, st1;
    #pragma unroll
    for (int i = 0; i < 16; ++i) { st0[i] = 0.f; st1[i] = 0.f; }
    __builtin_amdgcn_s_setprio(1);
    #pragma unroll
    for (int cs = 0; cs < 8; ++cs) {
      int co = cs * 32 + h * 16;  // byte offset of c-slice within 256B row
      bf16x8 kf0 = *reinterpret_cast<const bf16x8*>(kS[buf] + ((lq * 256 + co) ^ ((lq & 7) << 4)));
      st0 = __builtin_amdgcn_mfma_f32_32x32x16_bf16(kf0, qf[cs], st0, 0, 0, 0);
      int kr1 = 32 + lq;
      bf16x8 kf1 = *reinterpret_cast<const bf16x8*>(kS[buf] + ((kr1 * 256 + co) ^ ((kr1 & 7) << 4)));
      st1 = __builtin_amdgcn_mfma_f32_32x32x16_bf16(kf1, qf[cs], st1, 0, 0, 0);
    }
    __builtin_amdgcn_s_setprio(0);

    // online softmax: lane owns full q-row slice (32 of 64 k); pair lane l^32 has the rest
    float mt = st0[0];
    #pragma unroll
    for (int i = 1; i < 16; ++i) mt = fmaxf(mt, st0[i]);
    #pragma unroll
    for (int i = 0; i < 16; ++i) mt = fmaxf(mt, st1[i]);
    mt = fmaxf(mt, __shfl_xor(mt, 32));
    if (__any(mt > m2 + 8.f)) {  // defer-max THR=8 (base-2)
      float mn = fmaxf(m2, mt);
      float r = exp2f(m2 - mn);
      m2 = mn;
      lsum *= r;
      #pragma unroll
      for (int reg = 0; reg < 16; ++reg) {
        int qrow = (reg & 3) + 8 * (reg >> 2) + 4 * h;
        float rq = __shfl(r, qrow);
        #pragma unroll
        for (int cc = 0; cc < 4; ++cc) acc[cc][reg] *= rq;
      }
    }
    // P = exp2(S - m2) in-register; redistribute across lane-halves into PV A-frags
    bf16x8 pa[4];
    #pragma unroll
    for (int ks = 0; ks < 2; ++ks) {
      float p[16];
      #pragma unroll
      for (int i = 0; i < 16; ++i) {
        float sv = (ks == 0) ? st0[i] : st1[i];
        p[i] = exp2f(sv - m2);
        lsum += p[i];
      }
      #pragma unroll
      for (int kk = 0; kk < 2; ++kk) {
        int r0 = kk * 8, r1 = kk * 8 + 4;
        u32 a1 = cvtpk(p[r0 + 0], p[r0 + 1]);
        u32 a2 = cvtpk(p[r0 + 2], p[r0 + 3]);
        u32 b1 = cvtpk(p[r1 + 0], p[r1 + 1]);
        u32 b2 = cvtpk(p[r1 + 2], p[r1 + 3]);
        u32 sa1 = (u32)__shfl_xor((int)a1, 32);
        u32 sa2 = (u32)__shfl_xor((int)a2, 32);
        u32 sb1 = (u32)__shfl_xor((int)b1, 32);
        u32 sb2 = (u32)__shfl_xor((int)b2, 32);
        union { u32 wd[4]; bf16x8 v; } af;
        af.wd[0] = h ? sb1 : a1;
        af.wd[1] = h ? sb2 : a2;
        af.wd[2] = h ? b1 : sa1;
        af.wd[3] = h ? b2 : sa2;
        pa[ks * 2 + kk] = af.v;
      }
    }
    // PV: acc[cc] += P[q][k-slice ks2] * V[k][c = cc*32 + lq]
    __builtin_amdgcn_s_setprio(1);
    #pragma unroll
    for (int ks2 = 0; ks2 < 4; ++ks2) {
      int ko = ks2 * 32 + h * 16;  // byte offset of k-slice within 128B row
      #pragma unroll
      for (int cc = 0; cc < 4; ++cc) {
        int c = cc * 32 + lq;
        bf16x8 vf = *reinterpret_cast<const bf16x8*>(vS[buf] + ((c * 128 + ko) ^ ((c & 7) << 4)));
        acc[cc] = __builtin_amdgcn_mfma_f32_32x32x16_bf16(pa[ks2], vf, acc[cc], 0, 0, 0);
      }
    }
    __builtin_amdgcn_s_setprio(0);
    __syncthreads();  // drains prefetch + releases buf
    buf ^= 1;
  }
  // merge pair-lane partial sums (q-row split across l and l^32)
  lsum += __shfl_xor(lsum, 32);
  // write unnormalized partial O (bf16) + per-row (m, l)
  #pragma unroll
  for (int reg = 0; reg < 16; ++reg) {
    int qrow = (reg & 3) + 8 * (reg >> 2) + 4 * h;
    size_t row = (size_t)(sp * 16384 + b * 4096 + q0 + w * 32 + qrow);
    bf16_t* orow = (bf16_t*)opart + row * 128 + lq;
    #pragma unroll
    for (int cc = 0; cc < 4; ++cc)
      orow[cc * 32] = (bf16_t)acc[cc][reg];
  }
  if (l < 32) {
    size_t row = (size_t)(sp * 16384 + b * 4096 + q0 + w * 32 + l);
    ml[row * 2] = m2;
    ml[row * 2 + 1] = lsum;
  }
}

// ------- Proj GEMM + fused split-merge + bias + residual: out = x + Wp @ merge(opart) -------
__global__ __launch_bounds__(256) void proj_kernel(const float* __restrict__ wp,
                                                   const float* __restrict__ bp,
                                                   const u16* __restrict__ opart,
                                                   const float* __restrict__ ml,
                                                   const float* __restrict__ x,
                                                   float* __restrict__ out) {
  __shared__ char aS[16384];
  __shared__ char bS[16384];
  int b = blockIdx.z;
  int o0 = blockIdx.y * 64;
  int n0 = blockIdx.x * 64;
  int tid = threadIdx.x;
  #pragma unroll
  for (int i = 0; i < 8; ++i) {
    int chunk = tid + (i << 8);
    int o = chunk >> 5, cj = (chunk & 31) << 2;
    float4 f = *reinterpret_cast<const float4*>(wp + (o0 + o) * 128 + cj);
    u16 h0 = __builtin_bit_cast(u16, (bf16_t)f.x);
    u16 h1 = __builtin_bit_cast(u16, (bf16_t)f.y);
    u16 h2 = __builtin_bit_cast(u16, (bf16_t)f.z);
    u16 h3 = __builtin_bit_cast(u16, (bf16_t)f.w);
    *reinterpret_cast<ushort4*>(aS + ((o * 256 + cj * 2) ^ ((o & 7) << 4))) = make_ushort4(h0, h1, h2, h3);
  }
  // B-stage: merge 4 kv-splits inline -> bf16 h[n][c]
  #pragma unroll
  for (int i = 0; i < 4; ++i) {
    int chunk = tid + (i << 8);
    int n = chunk >> 4, ch = chunk & 15;
    size_t bn = (size_t)(b * 4096 + n0 + n);
    float m[4], lv[4];
    #pragma unroll
    for (int s = 0; s < 4; ++s) {
      m[s] = ml[((size_t)(s * 16384) + bn) * 2];
      lv[s] = ml[((size_t)(s * 16384) + bn) * 2 + 1];
    }
    float M = fmaxf(fmaxf(m[0], m[1]), fmaxf(m[2], m[3]));
    float wgt[4], L = 0.f;
    #pragma unroll
    for (int s = 0; s < 4; ++s) {
      wgt[s] = exp2f(m[s] - M);
      L += wgt[s] * lv[s];
    }
    float inv = 1.f / L;
    float o[8] = {0.f, 0.f, 0.f, 0.f, 0.f, 0.f, 0.f, 0.f};
    #pragma unroll
    for (int s = 0; s < 4; ++s) {
      uint4 pr = *reinterpret_cast<const uint4*>(opart + ((size_t)(s * 16384) + bn) * 128 + ch * 8);
      o[0] += wgt[s] * bfu2f(pr.x & 0xffffu);
      o[1] += wgt[s] * bfu2f(pr.x >> 16);
      o[2] += wgt[s] * bfu2f(pr.y & 0xffffu);
      o[3] += wgt[s] * bfu2f(pr.y >> 16);
      o[4] += wgt[s] * bfu2f(pr.z & 0xffffu);
      o[5] += wgt[s] * bfu2f(pr.z >> 16);
      o[6] += wgt[s] * bfu2f(pr.w & 0xffffu);
      o[7] += wgt[s] * bfu2f(pr.w >> 16);
    }
    u16 hh[8];
    #pragma unroll
    for (int e = 0; e < 8; ++e) hh[e] = __builtin_bit_cast(u16, (bf16_t)(o[e] * inv));
    uint4 packed;
    packed.x = (u32)hh[0] | ((u32)hh[1] << 16);
    packed.y = (u32)hh[2] | ((u32)hh[3] << 16);
    packed.z = (u32)hh[4] | ((u32)hh[5] << 16);
    packed.w = (u32)hh[6] | ((u32)hh[7] << 16);
    *reinterpret_cast<uint4*>(bS + ((n * 256 + ch * 16) ^ ((n & 7) << 4))) = packed;
  }
  __syncthreads();
  int w = tid >> 6, l = tid & 63, lr = l & 15, lg = l >> 4;
  f32x4 acc[4] = {{0,0,0,0},{0,0,0,0},{0,0,0,0},{0,0,0,0}};
  int orow = 16 * w + lr;
  #pragma unroll
  for (int kc = 0; kc < 4; ++kc) {
    int c2 = (lg * 8 + 32 * kc) * 2;
    bf16x8 a = *reinterpret_cast<const bf16x8*>(aS + ((orow * 256 + c2) ^ ((orow & 7) << 4)));
    #pragma unroll
    for (int fn = 0; fn < 4; ++fn) {
      int n = lr + 16 * fn;
      bf16x8 bb = *reinterpret_cast<const bf16x8*>(bS + ((n * 256 + c2) ^ ((n & 7) << 4)));
      acc[fn] = __builtin_amdgcn_mfma_f32_16x16x32_bf16(a, bb, acc[fn], 0, 0, 0);
    }
  }
  #pragma unroll
  for (int fn = 0; fn < 4; ++fn) {
    #pragma unroll
    for (int j = 0; j < 4; ++j) {
      int o = o0 + 16 * w + lg * 4 + j;
      int n = n0 + lr + 16 * fn;
      size_t idx = ((size_t)(b * 128 + o)) * 4096 + n;
      out[idx] = acc[fn][j] + bp[o] + x[idx];
    }
  }
}

extern "C" void kernel_launch(void* const* d_in, const int* in_sizes, int n_in,
                              void* d_out, int out_size, void* d_ws, size_t ws_size,
                              hipStream_t stream) {
  const float* x      = (const float*)d_in[0];
  const float* gamma  = (const float*)d_in[1];
  const float* beta   = (const float*)d_in[2];
  const float* w_qkv  = (const float*)d_in[3];
  const float* b_qkv  = (const float*)d_in[4];
  const float* w_proj = (const float*)d_in[5];
  const float* b_proj = (const float*)d_in[6];
  float* out = (float*)d_out;

  char* ws = (char*)d_ws;
  u16* xnt   = (u16*)(ws);               // 4 MB, [B,N,C] bf16
  u16* qt    = (u16*)(ws + (4u << 20));  // 4 MB, [B,N,C] (pre-scaled by alpha)
  u16* kt    = (u16*)(ws + (8u << 20));  // 4 MB, [B,N,C]
  u16* vv    = (u16*)(ws + (12u << 20)); // 4 MB, [B,C,N]
  u16* opart = (u16*)(ws + (16u << 20)); // 16 MB, [4 splits][B*N][C] bf16
  float* ml    = (float*)(ws + (48u << 20)); // 512 KB, [4 splits][B*N][2] f32
  float* parts = (float*)(ws + (49u << 20)); // 4 KB, GN partial sums [32][16][2]

  hipLaunchKernelGGL(gn_stats, dim3(512), dim3(256), 0, stream, x, parts);
  hipLaunchKernelGGL(gn_norm, dim3(256), dim3(256), 0, stream, x, gamma, beta, parts, xnt);
  hipLaunchKernelGGL(qkv_kernel, dim3(64, 2, 4), dim3(256), 0, stream, w_qkv, b_qkv, xnt, qt, kt, vv);
  hipLaunchKernelGGL(attn_kernel, dim3(32, 4, 4), dim3(256), 0, stream, qt, kt, vv, opart, ml);
  hipLaunchKernelGGL(proj_kernel, dim3(64, 2, 4), dim3(256), 0, stream, w_proj, b_proj, opart, ml, x, out);
}